// Round 1
// baseline (907.323 us; speedup 1.0000x reference)
//
#include <hip/hip_runtime.h>
#include <hip/hip_bf16.h>

#define HID 128
#define TILE_ROWS 32

// ---------------------------------------------------------------------------
// Generic Y[r,c] = X[r,:128] @ W[:128,c] + b[c]   (fp32, vector ALU)
// 256 threads, 32 rows/block. LDS: X tile 16KB + half-W 32KB = 48KB.
// Thread: 4 rows x 4 cols register tile, float4 LDS reads.
// ---------------------------------------------------------------------------
__global__ __launch_bounds__(256) void gemm128_k(
    const float* __restrict__ X, const float* __restrict__ W,
    const float* __restrict__ b, float* __restrict__ Y, int nrows) {
  __shared__ float Xs[TILE_ROWS][HID];
  __shared__ float Ws[64][HID];
  const int t = threadIdx.x;
  const int row0 = blockIdx.x * TILE_ROWS;

  // stage X tile (32x128 = 1024 float4, 4 per thread), zero-pad OOB rows
  #pragma unroll
  for (int it = 0; it < 4; ++it) {
    int idx4 = t + it * 256;
    int r = idx4 >> 5;
    int c = (idx4 & 31) << 2;
    float4 v = make_float4(0.f, 0.f, 0.f, 0.f);
    if (row0 + r < nrows)
      v = *(const float4*)(X + (size_t)(row0 + r) * HID + c);
    *(float4*)(&Xs[r][c]) = v;
  }

  const int c4 = (t & 31) << 2;  // column group
  const int rg = t >> 5;         // row group 0..7
  float acc[4][4];
  #pragma unroll
  for (int i = 0; i < 4; ++i)
    #pragma unroll
    for (int j = 0; j < 4; ++j) acc[i][j] = 0.f;

  for (int kk = 0; kk < HID; kk += 64) {
    __syncthreads();
    // stage W rows kk..kk+63 (8192 floats = 2048 float4, 8 per thread)
    #pragma unroll
    for (int it = 0; it < 8; ++it) {
      int idx4 = t + it * 256;
      int r = idx4 >> 5;
      int c = (idx4 & 31) << 2;
      *(float4*)(&Ws[r][c]) = *(const float4*)(W + (size_t)(kk + r) * HID + c);
    }
    __syncthreads();
    #pragma unroll 4
    for (int k = 0; k < 64; k += 4) {
      float xr[4][4];
      #pragma unroll
      for (int i = 0; i < 4; ++i) {
        float4 xv = *(const float4*)(&Xs[rg + i * 8][kk + k]);
        xr[i][0] = xv.x; xr[i][1] = xv.y; xr[i][2] = xv.z; xr[i][3] = xv.w;
      }
      #pragma unroll
      for (int kj = 0; kj < 4; ++kj) {
        float4 wv = *(const float4*)(&Ws[k + kj][c4]);
        #pragma unroll
        for (int i = 0; i < 4; ++i) {
          acc[i][0] += xr[i][kj] * wv.x;
          acc[i][1] += xr[i][kj] * wv.y;
          acc[i][2] += xr[i][kj] * wv.z;
          acc[i][3] += xr[i][kj] * wv.w;
        }
      }
    }
  }

  float4 bv = *(const float4*)(b + c4);
  #pragma unroll
  for (int i = 0; i < 4; ++i) {
    int row = row0 + rg + i * 8;
    if (row < nrows) {
      float4 o;
      o.x = acc[i][0] + bv.x; o.y = acc[i][1] + bv.y;
      o.z = acc[i][2] + bv.z; o.w = acc[i][3] + bv.w;
      *(float4*)(Y + (size_t)row * HID + c4) = o;
    }
  }
}

// ---------------------------------------------------------------------------
// Fused temporal score: ts[e,h] = sum_d (t_e.Wtq[:,h*16+d]+btq)(t_e.Wtk[:,h*16+d]+btk)
// 32 edges/block. [Wtq|Wtk] as one [32][256] LDS tile; register GEMM;
// tq/tk pairing via shfl_xor(32); head reduce via shfl_xor(1),(2).
// ---------------------------------------------------------------------------
__global__ __launch_bounds__(256) void temporal_k(
    const float* __restrict__ T, const float* __restrict__ Wtq,
    const float* __restrict__ Wtk, const float* __restrict__ btq,
    const float* __restrict__ btk, float* __restrict__ ts, int E) {
  __shared__ float W2s[32][256];
  __shared__ float TTs[32][36];  // transposed T tile, padded to 16B multiple
  const int t = threadIdx.x;
  const int e0 = blockIdx.x * 32;

  // stage T tile transposed: thread t loads float4 of row r=t>>3, k0=(t&7)*4
  {
    int r = t >> 3;
    int k0 = (t & 7) << 2;
    int ge = e0 + r;
    float4 v = make_float4(0.f, 0.f, 0.f, 0.f);
    if (ge < E) v = *(const float4*)(T + (size_t)ge * 32 + k0);
    TTs[k0 + 0][r] = v.x;
    TTs[k0 + 1][r] = v.y;
    TTs[k0 + 2][r] = v.z;
    TTs[k0 + 3][r] = v.w;
  }
  // stage [Wtq|Wtk]: 2048 float4, 8 per thread
  #pragma unroll
  for (int it = 0; it < 8; ++it) {
    int idx4 = t + it * 256;
    int k = idx4 >> 6;
    int c = (idx4 & 63) << 2;
    const float* src = (c < 128) ? (Wtq + (size_t)k * 128 + c)
                                 : (Wtk + (size_t)k * 128 + (c - 128));
    *(float4*)(&W2s[k][c]) = *(const float4*)src;
  }
  __syncthreads();

  const int idx = t & 63;   // lane
  const int eg = t >> 6;    // wave id -> edge group
  const int c4 = idx << 2;  // column in [0,256)
  float acc[8][4];
  #pragma unroll
  for (int i = 0; i < 8; ++i)
    #pragma unroll
    for (int j = 0; j < 4; ++j) acc[i][j] = 0.f;

  #pragma unroll 4
  for (int k = 0; k < 32; ++k) {
    float4 wv = *(const float4*)(&W2s[k][c4]);
    float4 ta = *(const float4*)(&TTs[k][eg * 8]);
    float4 tb = *(const float4*)(&TTs[k][eg * 8 + 4]);
    float tv[8] = {ta.x, ta.y, ta.z, ta.w, tb.x, tb.y, tb.z, tb.w};
    #pragma unroll
    for (int i = 0; i < 8; ++i) {
      acc[i][0] += tv[i] * wv.x;
      acc[i][1] += tv[i] * wv.y;
      acc[i][2] += tv[i] * wv.z;
      acc[i][3] += tv[i] * wv.w;
    }
  }

  float bias[4];
  {
    const float* bp = (idx < 32) ? (btq + c4) : (btk + (c4 - 128));
    float4 b4 = *(const float4*)bp;
    bias[0] = b4.x; bias[1] = b4.y; bias[2] = b4.z; bias[3] = b4.w;
  }
  #pragma unroll
  for (int i = 0; i < 8; ++i) {
    float s = 0.f;
    #pragma unroll
    for (int j = 0; j < 4; ++j) {
      float v = acc[i][j] + bias[j];
      float o = __shfl_xor(v, 32, 64);  // partner lane holds tk for same col
      s += v * o;
    }
    s += __shfl_xor(s, 1, 64);
    s += __shfl_xor(s, 2, 64);
    if ((idx & 3) == 0 && idx < 32) {
      int h = idx >> 2;
      int e = e0 + eg * 8 + i;
      if (e < E) ts[(size_t)e * 8 + h] = s;
    }
  }
}

// ---------------------------------------------------------------------------
// scores[e,h] += dot16(Q[src[e],h], K[tgt[e],h]) / 4   (in-place on ts)
// ---------------------------------------------------------------------------
__global__ __launch_bounds__(256) void qk_scores_k(
    const float* __restrict__ Qp, const float* __restrict__ Kp,
    const int* __restrict__ src, const int* __restrict__ tgt,
    float* __restrict__ scores, int E) {
  int gid = blockIdx.x * 256 + threadIdx.x;
  int e = gid >> 3;
  int h = gid & 7;
  if (e >= E) return;
  int s = src[e], g = tgt[e];
  const float4* q = (const float4*)(Qp + (size_t)s * HID + h * 16);
  const float4* k = (const float4*)(Kp + (size_t)g * HID + h * 16);
  float acc = 0.f;
  #pragma unroll
  for (int j = 0; j < 4; ++j) {
    float4 a = q[j], bb = k[j];
    acc += a.x * bb.x + a.y * bb.y + a.z * bb.z + a.w * bb.w;
  }
  size_t o = (size_t)e * 8 + h;
  scores[o] = acc * 0.25f + scores[o];
}

// ---------------------------------------------------------------------------
// CSR build
// ---------------------------------------------------------------------------
__global__ __launch_bounds__(256) void count_deg_k(const int* __restrict__ tgt,
                                                   int* __restrict__ deg, int E) {
  int gid = blockIdx.x * 256 + threadIdx.x;
  if (gid < E) atomicAdd(&deg[tgt[gid]], 1);
}

__global__ __launch_bounds__(1024) void scan_excl_k(const int* __restrict__ deg,
                                                    int* __restrict__ off, int n) {
  __shared__ int sd[1024];
  __shared__ int srun;
  const int t = threadIdx.x;
  if (t == 0) srun = 0;
  __syncthreads();
  for (int base = 0; base < n; base += 1024) {
    int i = base + t;
    int v = (i < n) ? deg[i] : 0;
    sd[t] = v;
    __syncthreads();
    for (int s = 1; s < 1024; s <<= 1) {
      int add = (t >= s) ? sd[t - s] : 0;
      __syncthreads();
      sd[t] += add;
      __syncthreads();
    }
    int run = srun;
    if (i < n) off[i] = run + sd[t] - v;
    int total = sd[1023];
    __syncthreads();
    if (t == 0) srun = run + total;
    __syncthreads();
  }
  if (t == 0) off[n] = srun;
}

__global__ __launch_bounds__(256) void scatter_k(const int* __restrict__ tgt,
                                                 const int* __restrict__ off,
                                                 int* __restrict__ cur,
                                                 int* __restrict__ elist, int E) {
  int gid = blockIdx.x * 256 + threadIdx.x;
  if (gid < E) {
    int n = tgt[gid];
    int p = atomicAdd(&cur[n], 1);
    elist[off[n] + p] = gid;
  }
}

// ---------------------------------------------------------------------------
// Per-node segment softmax + weighted aggregation. Block=128 (= H*hd), node
// per block, thread t = (h = t>>4, d = t&15). Atomic-free.
// ---------------------------------------------------------------------------
__global__ __launch_bounds__(128) void softmax_agg_k(
    const float* __restrict__ scores, const float* __restrict__ Vp,
    const int* __restrict__ src, const int* __restrict__ off,
    const int* __restrict__ elist, float* __restrict__ attn_w,
    float* __restrict__ agg, int N) {
  const int n = blockIdx.x;
  const int t = threadIdx.x;
  const int h = t >> 4;
  const int d = t & 15;
  const int s0 = off[n], s1 = off[n + 1];

  float m = -3.0e38f;
  for (int i = s0; i < s1; ++i) {
    int e = elist[i];
    m = fmaxf(m, scores[(size_t)e * 8 + h]);
  }
  float l = 0.f;
  for (int i = s0; i < s1; ++i) {
    int e = elist[i];
    l += __expf(scores[(size_t)e * 8 + h] - m);
  }
  float invl = (l > 0.f) ? 1.0f / l : 0.f;
  float acc = 0.f;
  for (int i = s0; i < s1; ++i) {
    int e = elist[i];
    float w = __expf(scores[(size_t)e * 8 + h] - m) * invl;
    int sn = src[e];
    acc += w * Vp[(size_t)sn * HID + t];
    if (d == 0) attn_w[(size_t)e * 8 + h] = w;
  }
  agg[(size_t)n * HID + t] = acc;
}

// ---------------------------------------------------------------------------
extern "C" void kernel_launch(void* const* d_in, const int* in_sizes, int n_in,
                              void* d_out, int out_size, void* d_ws, size_t ws_size,
                              hipStream_t stream) {
  const float* query    = (const float*)d_in[0];
  const float* key      = (const float*)d_in[1];
  const float* value    = (const float*)d_in[2];
  const float* temporal = (const float*)d_in[3];
  const int*   eidx     = (const int*)d_in[4];
  const float* Wq   = (const float*)d_in[5];
  const float* bq   = (const float*)d_in[6];
  const float* Wk   = (const float*)d_in[7];
  const float* bk   = (const float*)d_in[8];
  const float* Wv   = (const float*)d_in[9];
  const float* bv   = (const float*)d_in[10];
  const float* Wtq  = (const float*)d_in[11];
  const float* btq  = (const float*)d_in[12];
  const float* Wtk  = (const float*)d_in[13];
  const float* btk  = (const float*)d_in[14];
  const float* Wout = (const float*)d_in[15];
  const float* bout = (const float*)d_in[16];

  const int N = in_sizes[0] / HID;
  const int E = in_sizes[4] / 2;
  const int* src = eidx;
  const int* tgt = eidx + E;

  float* ws = (float*)d_ws;
  float* Qp     = ws;
  float* Kp     = Qp + (size_t)N * HID;
  float* Vp     = Kp + (size_t)N * HID;
  float* scores = Vp + (size_t)N * HID;
  int* deg   = (int*)(scores + (size_t)E * 8);
  int* cur   = deg + N;
  int* off   = cur + N;
  int* elist = off + (N + 1);
  float* agg = Qp;  // Qp dead after qk_scores_k

  hipMemsetAsync(deg, 0, sizeof(int) * 2 * (size_t)N, stream);  // deg + cur

  dim3 b256(256);
  const int tiles = (N + TILE_ROWS - 1) / TILE_ROWS;
  gemm128_k<<<tiles, b256, 0, stream>>>(query, Wq, bq, Qp, N);
  gemm128_k<<<tiles, b256, 0, stream>>>(key,   Wk, bk, Kp, N);
  gemm128_k<<<tiles, b256, 0, stream>>>(value, Wv, bv, Vp, N);

  temporal_k<<<(E + 31) / 32, b256, 0, stream>>>(temporal, Wtq, Wtk, btq, btk,
                                                 scores, E);
  qk_scores_k<<<(int)(((size_t)E * 8 + 255) / 256), b256, 0, stream>>>(
      Qp, Kp, src, tgt, scores, E);

  count_deg_k<<<(E + 255) / 256, b256, 0, stream>>>(tgt, deg, E);
  scan_excl_k<<<1, 1024, 0, stream>>>(deg, off, N);
  scatter_k<<<(E + 255) / 256, b256, 0, stream>>>(tgt, off, cur, elist, E);

  float* attn_w = (float*)d_out + (size_t)N * HID;
  softmax_agg_k<<<N, 128, 0, stream>>>(scores, Vp, src, off, elist, attn_w, agg, N);

  gemm128_k<<<tiles, b256, 0, stream>>>(agg, Wout, bout, (float*)d_out, N);
}

// Round 2
// 633.049 us; speedup vs baseline: 1.4333x; 1.4333x over previous
//
#include <hip/hip_runtime.h>
#include <hip/hip_bf16.h>

#define HID 128
#define TILE_ROWS 32
#define MAXD 128  // fast-path degree cap for softmax staging

// ---------------------------------------------------------------------------
// Generic Y[r,c] = X[r,:128] @ W[:128,c] + b[c]   (fp32, vector ALU)
// ---------------------------------------------------------------------------
__global__ __launch_bounds__(256) void gemm128_k(
    const float* __restrict__ X, const float* __restrict__ W,
    const float* __restrict__ b, float* __restrict__ Y, int nrows) {
  __shared__ float Xs[TILE_ROWS][HID];
  __shared__ float Ws[64][HID];
  const int t = threadIdx.x;
  const int row0 = blockIdx.x * TILE_ROWS;

  #pragma unroll
  for (int it = 0; it < 4; ++it) {
    int idx4 = t + it * 256;
    int r = idx4 >> 5;
    int c = (idx4 & 31) << 2;
    float4 v = make_float4(0.f, 0.f, 0.f, 0.f);
    if (row0 + r < nrows)
      v = *(const float4*)(X + (size_t)(row0 + r) * HID + c);
    *(float4*)(&Xs[r][c]) = v;
  }

  const int c4 = (t & 31) << 2;
  const int rg = t >> 5;
  float acc[4][4];
  #pragma unroll
  for (int i = 0; i < 4; ++i)
    #pragma unroll
    for (int j = 0; j < 4; ++j) acc[i][j] = 0.f;

  for (int kk = 0; kk < HID; kk += 64) {
    __syncthreads();
    #pragma unroll
    for (int it = 0; it < 8; ++it) {
      int idx4 = t + it * 256;
      int r = idx4 >> 5;
      int c = (idx4 & 31) << 2;
      *(float4*)(&Ws[r][c]) = *(const float4*)(W + (size_t)(kk + r) * HID + c);
    }
    __syncthreads();
    #pragma unroll 4
    for (int k = 0; k < 64; k += 4) {
      float xr[4][4];
      #pragma unroll
      for (int i = 0; i < 4; ++i) {
        float4 xv = *(const float4*)(&Xs[rg + i * 8][kk + k]);
        xr[i][0] = xv.x; xr[i][1] = xv.y; xr[i][2] = xv.z; xr[i][3] = xv.w;
      }
      #pragma unroll
      for (int kj = 0; kj < 4; ++kj) {
        float4 wv = *(const float4*)(&Ws[k + kj][c4]);
        #pragma unroll
        for (int i = 0; i < 4; ++i) {
          acc[i][0] += xr[i][kj] * wv.x;
          acc[i][1] += xr[i][kj] * wv.y;
          acc[i][2] += xr[i][kj] * wv.z;
          acc[i][3] += xr[i][kj] * wv.w;
        }
      }
    }
  }

  float4 bv = *(const float4*)(b + c4);
  #pragma unroll
  for (int i = 0; i < 4; ++i) {
    int row = row0 + rg + i * 8;
    if (row < nrows) {
      float4 o;
      o.x = acc[i][0] + bv.x; o.y = acc[i][1] + bv.y;
      o.z = acc[i][2] + bv.z; o.w = acc[i][3] + bv.w;
      *(float4*)(Y + (size_t)row * HID + c4) = o;
    }
  }
}

// ---------------------------------------------------------------------------
// Fused temporal score, persistent-block: W tile staged ONCE per block,
// grid-stride over 32-edge tiles.
// ---------------------------------------------------------------------------
__global__ __launch_bounds__(256) void temporal_k(
    const float* __restrict__ T, const float* __restrict__ Wtq,
    const float* __restrict__ Wtk, const float* __restrict__ btq,
    const float* __restrict__ btk, float* __restrict__ ts, int E, int ntiles) {
  __shared__ float W2s[32][256];
  __shared__ float TTs[32][36];
  const int t = threadIdx.x;

  #pragma unroll
  for (int it = 0; it < 8; ++it) {
    int idx4 = t + it * 256;
    int k = idx4 >> 6;
    int c = (idx4 & 63) << 2;
    const float* src = (c < 128) ? (Wtq + (size_t)k * 128 + c)
                                 : (Wtk + (size_t)k * 128 + (c - 128));
    *(float4*)(&W2s[k][c]) = *(const float4*)src;
  }

  const int idx = t & 63;
  const int eg = t >> 6;
  const int c4 = idx << 2;
  float bias[4];
  {
    const float* bp = (idx < 32) ? (btq + c4) : (btk + (c4 - 128));
    float4 b4 = *(const float4*)bp;
    bias[0] = b4.x; bias[1] = b4.y; bias[2] = b4.z; bias[3] = b4.w;
  }

  for (int tile = blockIdx.x; tile < ntiles; tile += gridDim.x) {
    const int e0 = tile * 32;
    __syncthreads();  // previous tile's reads done
    {
      int r = t >> 3;
      int k0 = (t & 7) << 2;
      int ge = e0 + r;
      float4 v = make_float4(0.f, 0.f, 0.f, 0.f);
      if (ge < E) v = *(const float4*)(T + (size_t)ge * 32 + k0);
      TTs[k0 + 0][r] = v.x;
      TTs[k0 + 1][r] = v.y;
      TTs[k0 + 2][r] = v.z;
      TTs[k0 + 3][r] = v.w;
    }
    __syncthreads();

    float acc[8][4];
    #pragma unroll
    for (int i = 0; i < 8; ++i)
      #pragma unroll
      for (int j = 0; j < 4; ++j) acc[i][j] = 0.f;

    #pragma unroll 4
    for (int k = 0; k < 32; ++k) {
      float4 wv = *(const float4*)(&W2s[k][c4]);
      float4 ta = *(const float4*)(&TTs[k][eg * 8]);
      float4 tb = *(const float4*)(&TTs[k][eg * 8 + 4]);
      float tv[8] = {ta.x, ta.y, ta.z, ta.w, tb.x, tb.y, tb.z, tb.w};
      #pragma unroll
      for (int i = 0; i < 8; ++i) {
        acc[i][0] += tv[i] * wv.x;
        acc[i][1] += tv[i] * wv.y;
        acc[i][2] += tv[i] * wv.z;
        acc[i][3] += tv[i] * wv.w;
      }
    }

    #pragma unroll
    for (int i = 0; i < 8; ++i) {
      float s = 0.f;
      #pragma unroll
      for (int j = 0; j < 4; ++j) {
        float v = acc[i][j] + bias[j];
        float o = __shfl_xor(v, 32, 64);
        s += v * o;
      }
      s += __shfl_xor(s, 1, 64);
      s += __shfl_xor(s, 2, 64);
      if ((idx & 3) == 0 && idx < 32) {
        int h = idx >> 2;
        int e = e0 + eg * 8 + i;
        if (e < E) ts[(size_t)e * 8 + h] = s;
      }
    }
  }
}

// ---------------------------------------------------------------------------
// scores[e,h] += dot16(Q[src[e],h], K[tgt[e],h]) / 4
// ---------------------------------------------------------------------------
__global__ __launch_bounds__(256) void qk_scores_k(
    const float* __restrict__ Qp, const float* __restrict__ Kp,
    const int* __restrict__ src, const int* __restrict__ tgt,
    float* __restrict__ scores, int E) {
  int gid = blockIdx.x * 256 + threadIdx.x;
  int e = gid >> 3;
  int h = gid & 7;
  if (e >= E) return;
  int s = src[e], g = tgt[e];
  const float4* q = (const float4*)(Qp + (size_t)s * HID + h * 16);
  const float4* k = (const float4*)(Kp + (size_t)g * HID + h * 16);
  float acc = 0.f;
  #pragma unroll
  for (int j = 0; j < 4; ++j) {
    float4 a = q[j], bb = k[j];
    acc += a.x * bb.x + a.y * bb.y + a.z * bb.z + a.w * bb.w;
  }
  size_t o = (size_t)e * 8 + h;
  scores[o] = acc * 0.25f + scores[o];
}

// ---------------------------------------------------------------------------
// CSR build: degree count, 3-kernel parallel scan, scatter
// ---------------------------------------------------------------------------
__global__ __launch_bounds__(256) void count_deg_k(const int* __restrict__ tgt,
                                                   int* __restrict__ deg, int E) {
  int gid = blockIdx.x * 256 + threadIdx.x;
  if (gid < E) atomicAdd(&deg[tgt[gid]], 1);
}

// block b sums deg[b*1024 .. b*1024+1024)
__global__ __launch_bounds__(256) void block_sum_k(const int* __restrict__ deg,
                                                   int* __restrict__ bsum, int n) {
  __shared__ int sd[256];
  const int base = blockIdx.x * 1024;
  const int t = threadIdx.x;
  int s = 0;
  #pragma unroll
  for (int j = 0; j < 4; ++j) {
    int i = base + t + j * 256;
    if (i < n) s += deg[i];
  }
  sd[t] = s;
  __syncthreads();
  for (int st = 128; st; st >>= 1) {
    if (t < st) sd[t] += sd[t + st];
    __syncthreads();
  }
  if (t == 0) bsum[blockIdx.x] = sd[0];
}

// exclusive scan over G (<=1024) partials
__global__ __launch_bounds__(1024) void scan_partials_k(const int* __restrict__ bsum,
                                                        int* __restrict__ boff, int G) {
  __shared__ int sd[1024];
  const int t = threadIdx.x;
  int v = (t < G) ? bsum[t] : 0;
  sd[t] = v;
  __syncthreads();
  for (int s = 1; s < 1024; s <<= 1) {
    int a = (t >= s) ? sd[t - s] : 0;
    __syncthreads();
    sd[t] += a;
    __syncthreads();
  }
  if (t < G) boff[t] = sd[t] - v;
}

// per-block exclusive scan of 1024 degs (4/thread) + boff
__global__ __launch_bounds__(256) void block_scan_k(const int* __restrict__ deg,
                                                    const int* __restrict__ boff,
                                                    int* __restrict__ off, int n) {
  __shared__ int sd[256];
  const int base = blockIdx.x * 1024;
  const int t = threadIdx.x;
  const int i0 = base + t * 4;
  int v[4];
  int s = 0;
  #pragma unroll
  for (int j = 0; j < 4; ++j) {
    v[j] = (i0 + j < n) ? deg[i0 + j] : 0;
    s += v[j];
  }
  const int own = s;
  sd[t] = s;
  __syncthreads();
  for (int st = 1; st < 256; st <<= 1) {
    int a = (t >= st) ? sd[t - st] : 0;
    __syncthreads();
    sd[t] += a;
    __syncthreads();
  }
  int acc = boff[blockIdx.x] + sd[t] - own;  // exclusive start for this thread
  #pragma unroll
  for (int j = 0; j < 4; ++j) {
    int idx = i0 + j;
    if (idx < n) {
      off[idx] = acc;
      acc += v[j];
      if (idx == n - 1) off[n] = acc;
    }
  }
}

__global__ __launch_bounds__(256) void scatter_k(const int* __restrict__ tgt,
                                                 const int* __restrict__ off,
                                                 int* __restrict__ cur,
                                                 int* __restrict__ elist, int E) {
  int gid = blockIdx.x * 256 + threadIdx.x;
  if (gid < E) {
    int n = tgt[gid];
    int p = atomicAdd(&cur[n], 1);
    elist[off[n] + p] = gid;
  }
}

// ---------------------------------------------------------------------------
// Per-node segment softmax + weighted aggregation, staged + lane-parallel.
// Block = 128 threads = H*hd; thread t = (h = t>>4, d = t&15).
// Fast path (deg<=128): stage elist/src/scores in LDS, 2 global passes total.
// ---------------------------------------------------------------------------
__global__ __launch_bounds__(128) void softmax_agg_k(
    const float* __restrict__ scores, const float* __restrict__ Vp,
    const int* __restrict__ src, const int* __restrict__ off,
    const int* __restrict__ elist, float* __restrict__ attn_w,
    float* __restrict__ agg, int N) {
  __shared__ int esh[MAXD];
  __shared__ int ssh[MAXD];
  __shared__ float sc[MAXD][9];  // padded stride to spread banks
  const int n = blockIdx.x;
  const int t = threadIdx.x;
  const int h = t >> 4;
  const int d = t & 15;
  const int s0 = off[n];
  const int deg = off[n + 1] - s0;

  if (deg <= MAXD) {
    // stage edge ids + src ids
    for (int i = t; i < deg; i += 128) {
      int e = elist[s0 + i];
      esh[i] = e;
      ssh[i] = src[e];
    }
    __syncthreads();
    // stage scores [deg][8]: thread (i0 = t>>3, h8 = t&7)
    {
      const int h8 = t & 7;
      for (int i = t >> 3; i < deg; i += 16)
        sc[i][h8] = scores[(size_t)esh[i] * 8 + h8];
    }
    __syncthreads();

    // lane-parallel max over this h's scores
    float m = -3.0e38f;
    for (int i = d; i < deg; i += 16) m = fmaxf(m, sc[i][h]);
    #pragma unroll
    for (int w = 8; w; w >>= 1) m = fmaxf(m, __shfl_xor(m, w, 16));

    // lane-parallel sum of exp; cache e_i back into LDS
    float l = 0.f;
    for (int i = d; i < deg; i += 16) {
      float e = __expf(sc[i][h] - m);
      sc[i][h] = e;
      l += e;
    }
    #pragma unroll
    for (int w = 8; w; w >>= 1) l += __shfl_xor(l, w, 16);
    float invl = (l > 0.f) ? 1.0f / l : 0.f;
    __syncthreads();

    // aggregation: every thread walks all edges for its own column t
    float acc = 0.f;
    for (int i = 0; i < deg; ++i) {
      float w = sc[i][h] * invl;
      acc += w * Vp[(size_t)ssh[i] * HID + t];
      if (d == 0) attn_w[(size_t)esh[i] * 8 + h] = w;
    }
    agg[(size_t)n * HID + t] = acc;
  } else {
    // general fallback (rare): unstaged, lane-parallel max/sum, serial agg
    float m = -3.0e38f;
    for (int i = d; i < deg; i += 16)
      m = fmaxf(m, scores[(size_t)elist[s0 + i] * 8 + h]);
    #pragma unroll
    for (int w = 8; w; w >>= 1) m = fmaxf(m, __shfl_xor(m, w, 16));

    float l = 0.f;
    for (int i = d; i < deg; i += 16)
      l += __expf(scores[(size_t)elist[s0 + i] * 8 + h] - m);
    #pragma unroll
    for (int w = 8; w; w >>= 1) l += __shfl_xor(l, w, 16);
    float invl = (l > 0.f) ? 1.0f / l : 0.f;

    float acc = 0.f;
    for (int i = 0; i < deg; ++i) {
      int e = elist[s0 + i];
      float w = __expf(scores[(size_t)e * 8 + h] - m) * invl;
      acc += w * Vp[(size_t)src[e] * HID + t];
      if (d == 0) attn_w[(size_t)e * 8 + h] = w;
    }
    agg[(size_t)n * HID + t] = acc;
  }
}

// ---------------------------------------------------------------------------
extern "C" void kernel_launch(void* const* d_in, const int* in_sizes, int n_in,
                              void* d_out, int out_size, void* d_ws, size_t ws_size,
                              hipStream_t stream) {
  const float* query    = (const float*)d_in[0];
  const float* key      = (const float*)d_in[1];
  const float* value    = (const float*)d_in[2];
  const float* temporal = (const float*)d_in[3];
  const int*   eidx     = (const int*)d_in[4];
  const float* Wq   = (const float*)d_in[5];
  const float* bq   = (const float*)d_in[6];
  const float* Wk   = (const float*)d_in[7];
  const float* bk   = (const float*)d_in[8];
  const float* Wv   = (const float*)d_in[9];
  const float* bv   = (const float*)d_in[10];
  const float* Wtq  = (const float*)d_in[11];
  const float* btq  = (const float*)d_in[12];
  const float* Wtk  = (const float*)d_in[13];
  const float* btk  = (const float*)d_in[14];
  const float* Wout = (const float*)d_in[15];
  const float* bout = (const float*)d_in[16];

  const int N = in_sizes[0] / HID;
  const int E = in_sizes[4] / 2;
  const int* src = eidx;
  const int* tgt = eidx + E;

  float* ws = (float*)d_ws;
  float* Qp     = ws;
  float* Kp     = Qp + (size_t)N * HID;
  float* Vp     = Kp + (size_t)N * HID;
  float* scores = Vp + (size_t)N * HID;
  int* deg   = (int*)(scores + (size_t)E * 8);
  int* cur   = deg + N;
  int* off   = cur + N;
  int* elist = off + (N + 1);
  int* bsum  = elist + E;
  int* boff  = bsum + 1024;
  float* agg = Qp;  // Qp dead after qk_scores_k

  const int G = (N + 1023) / 1024;  // scan blocks (<=1024 assumed)

  hipMemsetAsync(deg, 0, sizeof(int) * 2 * (size_t)N, stream);  // deg + cur

  dim3 b256(256);
  const int tiles = (N + TILE_ROWS - 1) / TILE_ROWS;
  gemm128_k<<<tiles, b256, 0, stream>>>(query, Wq, bq, Qp, N);
  gemm128_k<<<tiles, b256, 0, stream>>>(key,   Wk, bk, Kp, N);
  gemm128_k<<<tiles, b256, 0, stream>>>(value, Wv, bv, Vp, N);

  const int ntiles = (E + 31) / 32;
  temporal_k<<<2048, b256, 0, stream>>>(temporal, Wtq, Wtk, btq, btk,
                                        scores, E, ntiles);
  qk_scores_k<<<(int)(((size_t)E * 8 + 255) / 256), b256, 0, stream>>>(
      Qp, Kp, src, tgt, scores, E);

  count_deg_k<<<(E + 255) / 256, b256, 0, stream>>>(tgt, deg, E);
  block_sum_k<<<G, b256, 0, stream>>>(deg, bsum, N);
  scan_partials_k<<<1, 1024, 0, stream>>>(bsum, boff, G);
  block_scan_k<<<G, b256, 0, stream>>>(deg, boff, off, N);
  scatter_k<<<(E + 255) / 256, b256, 0, stream>>>(tgt, off, cur, elist, E);

  float* attn_w = (float*)d_out + (size_t)N * HID;
  softmax_agg_k<<<N, 128, 0, stream>>>(scores, Vp, src, off, elist, attn_w, agg, N);

  gemm128_k<<<tiles, b256, 0, stream>>>(agg, Wout, bout, (float*)d_out, N);
}

// Round 3
// 506.544 us; speedup vs baseline: 1.7912x; 1.2497x over previous
//
#include <hip/hip_runtime.h>
#include <hip/hip_bf16.h>

#define HID 128
#define MAXD 128

typedef __attribute__((ext_vector_type(8))) short bfrag8;
typedef __attribute__((ext_vector_type(4))) float facc4;

// f32 -> bf16 bits, round-to-nearest-even
__device__ inline short f2bf(float x) {
  unsigned u = __builtin_bit_cast(unsigned, x);
  u += 0x7fffu + ((u >> 16) & 1u);
  return (short)(u >> 16);
}
__device__ inline float bf2f(short s) {
  unsigned u = ((unsigned)(unsigned short)s) << 16;
  return __builtin_bit_cast(float, u);
}

__device__ inline void store_out(float* Y, size_t i, float v) { Y[i] = v; }
__device__ inline void store_out(short* Y, size_t i, float v) { Y[i] = f2bf(v); }

// ---------------------------------------------------------------------------
// Y[r,c] = X[r,:128] @ W[:128,c] + b[c] via bf16 MFMA with split-X (hi+lo).
// Block 256 (4 waves), 64 rows/block (16 rows/wave). W staged once in LDS as
// fragment-linear bf16 chunks: [ct 8][kt 4][g 4][c 16] x 16B.
// ---------------------------------------------------------------------------
template <typename OT>
__global__ __launch_bounds__(256) void gemm_mfma_k(
    const float* __restrict__ X, const float* __restrict__ W,
    const float* __restrict__ b, OT* __restrict__ Y, int nrows) {
  __shared__ short Ws[8 * 4 * 4 * 16 * 8];  // 32KB
  const int t = threadIdx.x;

  #pragma unroll
  for (int it = 0; it < 8; ++it) {
    int chunk = t + it * 256;  // 2048 chunks
    int c  = chunk & 15;
    int g  = (chunk >> 4) & 3;
    int kt = (chunk >> 6) & 3;
    int ct = chunk >> 8;
    int col = ct * 16 + c;
    int k0 = kt * 32 + g * 8;
    bfrag8 v;
    #pragma unroll
    for (int i = 0; i < 8; ++i) v[i] = f2bf(W[(size_t)(k0 + i) * HID + col]);
    *(bfrag8*)(&Ws[chunk * 8]) = v;
  }
  __syncthreads();

  const int w  = t >> 6;
  const int l  = t & 63;
  const int lr = l & 15;
  const int g  = l >> 4;
  const int row0 = blockIdx.x * 64 + w * 16;
  const int arow = min(row0 + lr, nrows - 1);

  facc4 acc[8];
  #pragma unroll
  for (int i = 0; i < 8; ++i) acc[i] = (facc4){0.f, 0.f, 0.f, 0.f};

  #pragma unroll
  for (int kt = 0; kt < 4; ++kt) {
    const float* xp = X + (size_t)arow * HID + kt * 32 + g * 8;
    float xv[8];
    *(facc4*)(xv)     = *(const facc4*)(xp);
    *(facc4*)(xv + 4) = *(const facc4*)(xp + 4);
    bfrag8 ahi, alo;
    #pragma unroll
    for (int i = 0; i < 8; ++i) {
      short h = f2bf(xv[i]);
      ahi[i] = h;
      alo[i] = f2bf(xv[i] - bf2f(h));
    }
    #pragma unroll
    for (int ct = 0; ct < 8; ++ct) {
      bfrag8 bf = *(const bfrag8*)(&Ws[(((ct * 4 + kt) * 4 + g) * 16 + lr) * 8]);
      acc[ct] = __builtin_amdgcn_mfma_f32_16x16x32_bf16(alo, bf, acc[ct], 0, 0, 0);
      acc[ct] = __builtin_amdgcn_mfma_f32_16x16x32_bf16(ahi, bf, acc[ct], 0, 0, 0);
    }
  }

  #pragma unroll
  for (int ct = 0; ct < 8; ++ct) {
    int col = ct * 16 + lr;
    float bias = b[col];
    #pragma unroll
    for (int r = 0; r < 4; ++r) {
      int row = row0 + g * 4 + r;
      if (row < nrows)
        store_out(Y, (size_t)row * HID + col, acc[ct][r] + bias);
    }
  }
}

// ---------------------------------------------------------------------------
// Temporal scores via MFMA: ts[e,h] = sum_c (T@Wtq+btq)[e,h*16+c]*(T@Wtk+btk)[..]
// 64 edges/block (16/wave). [Wtq|Wtk] staged once per block as frag chunks:
// [qk 2][ct 8][g 4][c 16] x 16B. Split-T for accuracy. Persistent grid.
// ---------------------------------------------------------------------------
__global__ __launch_bounds__(256) void temporal_mfma_k(
    const float* __restrict__ T, const float* __restrict__ Wtq,
    const float* __restrict__ Wtk, const float* __restrict__ btq,
    const float* __restrict__ btk, float* __restrict__ ts, int E, int ntiles) {
  __shared__ short Ws[2 * 8 * 4 * 16 * 8];  // 16KB
  const int t = threadIdx.x;

  #pragma unroll
  for (int it = 0; it < 4; ++it) {
    int chunk = t + it * 256;  // 1024 chunks
    int c  = chunk & 15;
    int g  = (chunk >> 4) & 3;
    int ct = (chunk >> 6) & 7;
    int qk = chunk >> 9;
    const float* Wsrc = qk ? Wtk : Wtq;
    int col = ct * 16 + c;
    int k0 = g * 8;
    bfrag8 v;
    #pragma unroll
    for (int i = 0; i < 8; ++i) v[i] = f2bf(Wsrc[(size_t)(k0 + i) * HID + col]);
    *(bfrag8*)(&Ws[chunk * 8]) = v;
  }
  __syncthreads();

  const int w  = t >> 6;
  const int l  = t & 63;
  const int lr = l & 15;
  const int g  = l >> 4;
  float bq_l[8], bk_l[8];
  #pragma unroll
  for (int h = 0; h < 8; ++h) {
    bq_l[h] = btq[h * 16 + lr];
    bk_l[h] = btk[h * 16 + lr];
  }

  for (int tile = blockIdx.x; tile < ntiles; tile += gridDim.x) {
    const int e0 = tile * 64 + w * 16;
    const int ar = min(e0 + lr, E - 1);
    const float* tp = T + (size_t)ar * 32 + g * 8;
    float xv[8];
    *(facc4*)(xv)     = *(const facc4*)(tp);
    *(facc4*)(xv + 4) = *(const facc4*)(tp + 4);
    bfrag8 ahi, alo;
    #pragma unroll
    for (int i = 0; i < 8; ++i) {
      short h = f2bf(xv[i]);
      ahi[i] = h;
      alo[i] = f2bf(xv[i] - bf2f(h));
    }

    facc4 accq[8], acck[8];
    #pragma unroll
    for (int ct = 0; ct < 8; ++ct) {
      facc4 z = (facc4){0.f, 0.f, 0.f, 0.f};
      bfrag8 bq = *(const bfrag8*)(&Ws[(((0 * 8 + ct) * 4 + g) * 16 + lr) * 8]);
      facc4 aq = __builtin_amdgcn_mfma_f32_16x16x32_bf16(alo, bq, z, 0, 0, 0);
      accq[ct]  = __builtin_amdgcn_mfma_f32_16x16x32_bf16(ahi, bq, aq, 0, 0, 0);
      bfrag8 bk = *(const bfrag8*)(&Ws[(((1 * 8 + ct) * 4 + g) * 16 + lr) * 8]);
      facc4 ak = __builtin_amdgcn_mfma_f32_16x16x32_bf16(alo, bk, z, 0, 0, 0);
      acck[ct]  = __builtin_amdgcn_mfma_f32_16x16x32_bf16(ahi, bk, ak, 0, 0, 0);
    }

    #pragma unroll
    for (int h = 0; h < 8; ++h) {
      float s[4];
      #pragma unroll
      for (int r = 0; r < 4; ++r) {
        float qv = accq[h][r] + bq_l[h];
        float kv = acck[h][r] + bk_l[h];
        float p = qv * kv;
        p += __shfl_xor(p, 1, 16);
        p += __shfl_xor(p, 2, 16);
        p += __shfl_xor(p, 4, 16);
        p += __shfl_xor(p, 8, 16);
        s[r] = p;
      }
      if (lr == h) {
        #pragma unroll
        for (int r = 0; r < 4; ++r) {
          int e = e0 + g * 4 + r;
          if (e < E) ts[(size_t)e * 8 + h] = s[r];
        }
      }
    }
  }
}

// ---------------------------------------------------------------------------
// CSR build
// ---------------------------------------------------------------------------
__global__ __launch_bounds__(256) void count_deg_k(const int* __restrict__ tgt,
                                                   int* __restrict__ deg, int E) {
  int gid = blockIdx.x * 256 + threadIdx.x;
  if (gid < E) atomicAdd(&deg[tgt[gid]], 1);
}

__global__ __launch_bounds__(256) void block_sum_k(const int* __restrict__ deg,
                                                   int* __restrict__ bsum, int n) {
  __shared__ int sd[256];
  const int base = blockIdx.x * 1024;
  const int t = threadIdx.x;
  int s = 0;
  #pragma unroll
  for (int j = 0; j < 4; ++j) {
    int i = base + t + j * 256;
    if (i < n) s += deg[i];
  }
  sd[t] = s;
  __syncthreads();
  for (int st = 128; st; st >>= 1) {
    if (t < st) sd[t] += sd[t + st];
    __syncthreads();
  }
  if (t == 0) bsum[blockIdx.x] = sd[0];
}

__global__ __launch_bounds__(1024) void scan_partials_k(const int* __restrict__ bsum,
                                                        int* __restrict__ boff, int G) {
  __shared__ int sd[1024];
  const int t = threadIdx.x;
  int v = (t < G) ? bsum[t] : 0;
  sd[t] = v;
  __syncthreads();
  for (int s = 1; s < 1024; s <<= 1) {
    int a = (t >= s) ? sd[t - s] : 0;
    __syncthreads();
    sd[t] += a;
    __syncthreads();
  }
  if (t < G) boff[t] = sd[t] - v;
}

__global__ __launch_bounds__(256) void block_scan_k(const int* __restrict__ deg,
                                                    const int* __restrict__ boff,
                                                    int* __restrict__ off, int n) {
  __shared__ int sd[256];
  const int base = blockIdx.x * 1024;
  const int t = threadIdx.x;
  const int i0 = base + t * 4;
  int v[4];
  int s = 0;
  #pragma unroll
  for (int j = 0; j < 4; ++j) {
    v[j] = (i0 + j < n) ? deg[i0 + j] : 0;
    s += v[j];
  }
  const int own = s;
  sd[t] = s;
  __syncthreads();
  for (int st = 1; st < 256; st <<= 1) {
    int a = (t >= st) ? sd[t - st] : 0;
    __syncthreads();
    sd[t] += a;
    __syncthreads();
  }
  int acc = boff[blockIdx.x] + sd[t] - own;
  #pragma unroll
  for (int j = 0; j < 4; ++j) {
    int idx = i0 + j;
    if (idx < n) {
      off[idx] = acc;
      acc += v[j];
      if (idx == n - 1) off[n] = acc;
    }
  }
}

__global__ __launch_bounds__(256) void scatter_k(const int* __restrict__ tgt,
                                                 const int* __restrict__ off,
                                                 int* __restrict__ cur,
                                                 int* __restrict__ elist, int E) {
  int gid = blockIdx.x * 256 + threadIdx.x;
  if (gid < E) {
    int n = tgt[gid];
    int p = atomicAdd(&cur[n], 1);
    elist[off[n] + p] = gid;
  }
}

// ---------------------------------------------------------------------------
// Per-node: QK scores (K row is block-uniform) + segment softmax + weighted
// aggregation. Block=128, thread t=(h=t>>4, d=t&15). Q/K/V are bf16.
// ---------------------------------------------------------------------------
__global__ __launch_bounds__(128) void softmax_agg_k(
    const float* __restrict__ tscores, const short* __restrict__ Qp,
    const short* __restrict__ Kp, const short* __restrict__ Vp,
    const int* __restrict__ src, const int* __restrict__ off,
    const int* __restrict__ elist, float* __restrict__ attn_w,
    float* __restrict__ agg, int N) {
  __shared__ int esh[MAXD];
  __shared__ int ssh[MAXD];
  __shared__ float sc[MAXD][9];
  const int n = blockIdx.x;
  const int t = threadIdx.x;
  const int h = t >> 4;
  const int d = t & 15;
  const int s0 = off[n];
  const int deg = off[n + 1] - s0;
  const float kv = bf2f(Kp[(size_t)n * HID + t]);

  if (deg <= MAXD) {
    for (int i = t; i < deg; i += 128) {
      int e = elist[s0 + i];
      esh[i] = e;
      ssh[i] = src[e];
    }
    __syncthreads();
    for (int i = 0; i < deg; ++i) {
      float p = bf2f(Qp[(size_t)ssh[i] * HID + t]) * kv;
      p += __shfl_xor(p, 1, 16);
      p += __shfl_xor(p, 2, 16);
      p += __shfl_xor(p, 4, 16);
      p += __shfl_xor(p, 8, 16);
      if (d == 0) sc[i][h] = tscores[(size_t)esh[i] * 8 + h] + p * 0.25f;
    }
    __syncthreads();

    float m = -3.0e38f;
    for (int i = d; i < deg; i += 16) m = fmaxf(m, sc[i][h]);
    #pragma unroll
    for (int w = 8; w; w >>= 1) m = fmaxf(m, __shfl_xor(m, w, 16));

    float l = 0.f;
    for (int i = d; i < deg; i += 16) {
      float e = __expf(sc[i][h] - m);
      sc[i][h] = e;
      l += e;
    }
    #pragma unroll
    for (int w = 8; w; w >>= 1) l += __shfl_xor(l, w, 16);
    float invl = (l > 0.f) ? 1.0f / l : 0.f;
    __syncthreads();

    float acc = 0.f;
    for (int i = 0; i < deg; ++i) {
      float wgt = sc[i][h] * invl;
      acc += wgt * bf2f(Vp[(size_t)ssh[i] * HID + t]);
      if (d == 0) attn_w[(size_t)esh[i] * 8 + h] = wgt;
    }
    agg[(size_t)n * HID + t] = acc;
  } else {
    // fallback: compute score per edge on the fly (all lanes get full sum)
    float m = -3.0e38f;
    for (int i = 0; i < deg; ++i) {
      int e = elist[s0 + i];
      float p = bf2f(Qp[(size_t)src[e] * HID + t]) * kv;
      p += __shfl_xor(p, 1, 16);
      p += __shfl_xor(p, 2, 16);
      p += __shfl_xor(p, 4, 16);
      p += __shfl_xor(p, 8, 16);
      m = fmaxf(m, tscores[(size_t)e * 8 + h] + p * 0.25f);
    }
    float l = 0.f;
    for (int i = 0; i < deg; ++i) {
      int e = elist[s0 + i];
      float p = bf2f(Qp[(size_t)src[e] * HID + t]) * kv;
      p += __shfl_xor(p, 1, 16);
      p += __shfl_xor(p, 2, 16);
      p += __shfl_xor(p, 4, 16);
      p += __shfl_xor(p, 8, 16);
      l += __expf(tscores[(size_t)e * 8 + h] + p * 0.25f - m);
    }
    float invl = (l > 0.f) ? 1.0f / l : 0.f;
    float acc = 0.f;
    for (int i = 0; i < deg; ++i) {
      int e = elist[s0 + i];
      float p = bf2f(Qp[(size_t)src[e] * HID + t]) * kv;
      p += __shfl_xor(p, 1, 16);
      p += __shfl_xor(p, 2, 16);
      p += __shfl_xor(p, 4, 16);
      p += __shfl_xor(p, 8, 16);
      float wgt = __expf(tscores[(size_t)e * 8 + h] + p * 0.25f - m) * invl;
      acc += wgt * bf2f(Vp[(size_t)src[e] * HID + t]);
      if (d == 0) attn_w[(size_t)e * 8 + h] = wgt;
    }
    agg[(size_t)n * HID + t] = acc;
  }
}

// ---------------------------------------------------------------------------
extern "C" void kernel_launch(void* const* d_in, const int* in_sizes, int n_in,
                              void* d_out, int out_size, void* d_ws, size_t ws_size,
                              hipStream_t stream) {
  const float* query    = (const float*)d_in[0];
  const float* key      = (const float*)d_in[1];
  const float* value    = (const float*)d_in[2];
  const float* temporal = (const float*)d_in[3];
  const int*   eidx     = (const int*)d_in[4];
  const float* Wq   = (const float*)d_in[5];
  const float* bq   = (const float*)d_in[6];
  const float* Wk   = (const float*)d_in[7];
  const float* bk   = (const float*)d_in[8];
  const float* Wv   = (const float*)d_in[9];
  const float* bv   = (const float*)d_in[10];
  const float* Wtq  = (const float*)d_in[11];
  const float* btq  = (const float*)d_in[12];
  const float* Wtk  = (const float*)d_in[13];
  const float* btk  = (const float*)d_in[14];
  const float* Wout = (const float*)d_in[15];
  const float* bout = (const float*)d_in[16];

  const int N = in_sizes[0] / HID;
  const int E = in_sizes[4] / 2;
  const int* src = eidx;
  const int* tgt = eidx + E;

  char* ws = (char*)d_ws;
  short* Qp = (short*)ws;                      ws += (size_t)N * HID * 2;
  short* Kp = (short*)ws;                      ws += (size_t)N * HID * 2;
  short* Vp = (short*)ws;                      ws += (size_t)N * HID * 2;
  float* tscores = (float*)ws;                 ws += (size_t)E * 8 * 4;
  float* agg = (float*)ws;                     ws += (size_t)N * HID * 4;
  int* deg   = (int*)ws;                       ws += (size_t)N * 4;
  int* cur   = (int*)ws;                       ws += (size_t)N * 4;
  int* off   = (int*)ws;                       ws += (size_t)(N + 1) * 4;
  int* elist = (int*)ws;                       ws += (size_t)E * 4;
  int* bsum  = (int*)ws;                       ws += 1024 * 4;
  int* boff  = (int*)ws;

  const int G = (N + 1023) / 1024;

  hipMemsetAsync(deg, 0, sizeof(int) * 2 * (size_t)N, stream);  // deg + cur

  dim3 b256(256);
  const int gblk = (N + 63) / 64;
  gemm_mfma_k<short><<<gblk, b256, 0, stream>>>(query, Wq, bq, Qp, N);
  gemm_mfma_k<short><<<gblk, b256, 0, stream>>>(key,   Wk, bk, Kp, N);
  gemm_mfma_k<short><<<gblk, b256, 0, stream>>>(value, Wv, bv, Vp, N);

  temporal_mfma_k<<<2048, b256, 0, stream>>>(temporal, Wtq, Wtk, btq, btk,
                                             tscores, E, (E + 63) / 64);

  count_deg_k<<<(E + 255) / 256, b256, 0, stream>>>(tgt, deg, E);
  block_sum_k<<<G, b256, 0, stream>>>(deg, bsum, N);
  scan_partials_k<<<1, 1024, 0, stream>>>(bsum, boff, G);
  block_scan_k<<<G, b256, 0, stream>>>(deg, boff, off, N);
  scatter_k<<<(E + 255) / 256, b256, 0, stream>>>(tgt, off, cur, elist, E);

  float* attn_w = (float*)d_out + (size_t)N * HID;
  softmax_agg_k<<<N, 128, 0, stream>>>(tscores, Qp, Kp, Vp, src, off, elist,
                                       attn_w, agg, N);

  gemm_mfma_k<float><<<gblk, b256, 0, stream>>>(agg, Wout, bout, (float*)d_out, N);
}

// Round 4
// 363.541 us; speedup vs baseline: 2.4958x; 1.3934x over previous
//
#include <hip/hip_runtime.h>
#include <hip/hip_bf16.h>

#define HID 128
#define MAXD 64  // per-node fast-path degree cap (Poisson(6) max ~25)

typedef __attribute__((ext_vector_type(8))) short bfrag8;
typedef __attribute__((ext_vector_type(4))) short bf4;
typedef __attribute__((ext_vector_type(4))) float facc4;

// f32 -> bf16 bits, round-to-nearest-even
__device__ inline short f2bf(float x) {
  unsigned u = __builtin_bit_cast(unsigned, x);
  u += 0x7fffu + ((u >> 16) & 1u);
  return (short)(u >> 16);
}
__device__ inline float bf2f(short s) {
  unsigned u = ((unsigned)(unsigned short)s) << 16;
  return __builtin_bit_cast(float, u);
}

__device__ inline void store_out(float* Y, size_t i, float v) { Y[i] = v; }
__device__ inline void store_out(short* Y, size_t i, float v) { Y[i] = f2bf(v); }

// ---------------------------------------------------------------------------
// Y[r,c] = X[r,:128] @ W[:128,c] + b[c] via bf16 MFMA.
// IT=float: split-X (hi+lo, 2 MFMA). IT=short(bf16): direct (1 MFMA).
// Block 256 (4 waves), 64 rows/block. W staged once in LDS as fragment-linear
// bf16 chunks: [ct 8][kt 4][g 4][c 16] x 16B.
// ---------------------------------------------------------------------------
template <typename IT, typename OT>
__global__ __launch_bounds__(256) void gemm_mfma_k(
    const IT* __restrict__ X, const float* __restrict__ W,
    const float* __restrict__ b, OT* __restrict__ Y, int nrows) {
  __shared__ short Ws[8 * 4 * 4 * 16 * 8];  // 32KB
  const int t = threadIdx.x;

  #pragma unroll
  for (int it = 0; it < 8; ++it) {
    int chunk = t + it * 256;  // 2048 chunks
    int c  = chunk & 15;
    int g  = (chunk >> 4) & 3;
    int kt = (chunk >> 6) & 3;
    int ct = chunk >> 8;
    int col = ct * 16 + c;
    int k0 = kt * 32 + g * 8;
    bfrag8 v;
    #pragma unroll
    for (int i = 0; i < 8; ++i) v[i] = f2bf(W[(size_t)(k0 + i) * HID + col]);
    *(bfrag8*)(&Ws[chunk * 8]) = v;
  }
  __syncthreads();

  const int w  = t >> 6;
  const int l  = t & 63;
  const int lr = l & 15;
  const int g  = l >> 4;
  const int row0 = blockIdx.x * 64 + w * 16;
  const int arow = min(row0 + lr, nrows - 1);

  facc4 acc[8];
  #pragma unroll
  for (int i = 0; i < 8; ++i) acc[i] = (facc4){0.f, 0.f, 0.f, 0.f};

  #pragma unroll
  for (int kt = 0; kt < 4; ++kt) {
    if constexpr (sizeof(IT) == 4) {
      const float* xp = (const float*)X + (size_t)arow * HID + kt * 32 + g * 8;
      float xv[8];
      *(facc4*)(xv)     = *(const facc4*)(xp);
      *(facc4*)(xv + 4) = *(const facc4*)(xp + 4);
      bfrag8 ahi, alo;
      #pragma unroll
      for (int i = 0; i < 8; ++i) {
        short h = f2bf(xv[i]);
        ahi[i] = h;
        alo[i] = f2bf(xv[i] - bf2f(h));
      }
      #pragma unroll
      for (int ct = 0; ct < 8; ++ct) {
        bfrag8 bf = *(const bfrag8*)(&Ws[(((ct * 4 + kt) * 4 + g) * 16 + lr) * 8]);
        acc[ct] = __builtin_amdgcn_mfma_f32_16x16x32_bf16(alo, bf, acc[ct], 0, 0, 0);
        acc[ct] = __builtin_amdgcn_mfma_f32_16x16x32_bf16(ahi, bf, acc[ct], 0, 0, 0);
      }
    } else {
      bfrag8 a = *(const bfrag8*)((const short*)X + (size_t)arow * HID + kt * 32 + g * 8);
      #pragma unroll
      for (int ct = 0; ct < 8; ++ct) {
        bfrag8 bf = *(const bfrag8*)(&Ws[(((ct * 4 + kt) * 4 + g) * 16 + lr) * 8]);
        acc[ct] = __builtin_amdgcn_mfma_f32_16x16x32_bf16(a, bf, acc[ct], 0, 0, 0);
      }
    }
  }

  #pragma unroll
  for (int ct = 0; ct < 8; ++ct) {
    int col = ct * 16 + lr;
    float bias = b[col];
    #pragma unroll
    for (int r = 0; r < 4; ++r) {
      int row = row0 + g * 4 + r;
      if (row < nrows)
        store_out(Y, (size_t)row * HID + col, acc[ct][r] + bias);
    }
  }
}

// ---------------------------------------------------------------------------
// Temporal scores via MFMA (split-T), persistent grid, 64 edges/block.
// ---------------------------------------------------------------------------
__global__ __launch_bounds__(256) void temporal_mfma_k(
    const float* __restrict__ T, const float* __restrict__ Wtq,
    const float* __restrict__ Wtk, const float* __restrict__ btq,
    const float* __restrict__ btk, float* __restrict__ ts, int E, int ntiles) {
  __shared__ short Ws[2 * 8 * 4 * 16 * 8];  // 16KB
  const int t = threadIdx.x;

  #pragma unroll
  for (int it = 0; it < 4; ++it) {
    int chunk = t + it * 256;
    int c  = chunk & 15;
    int g  = (chunk >> 4) & 3;
    int ct = (chunk >> 6) & 7;
    int qk = chunk >> 9;
    const float* Wsrc = qk ? Wtk : Wtq;
    int col = ct * 16 + c;
    int k0 = g * 8;
    bfrag8 v;
    #pragma unroll
    for (int i = 0; i < 8; ++i) v[i] = f2bf(Wsrc[(size_t)(k0 + i) * HID + col]);
    *(bfrag8*)(&Ws[chunk * 8]) = v;
  }
  __syncthreads();

  const int w  = t >> 6;
  const int l  = t & 63;
  const int lr = l & 15;
  const int g  = l >> 4;
  float bq_l[8], bk_l[8];
  #pragma unroll
  for (int h = 0; h < 8; ++h) {
    bq_l[h] = btq[h * 16 + lr];
    bk_l[h] = btk[h * 16 + lr];
  }

  for (int tile = blockIdx.x; tile < ntiles; tile += gridDim.x) {
    const int e0 = tile * 64 + w * 16;
    const int ar = min(e0 + lr, E - 1);
    const float* tp = T + (size_t)ar * 32 + g * 8;
    float xv[8];
    *(facc4*)(xv)     = *(const facc4*)(tp);
    *(facc4*)(xv + 4) = *(const facc4*)(tp + 4);
    bfrag8 ahi, alo;
    #pragma unroll
    for (int i = 0; i < 8; ++i) {
      short h = f2bf(xv[i]);
      ahi[i] = h;
      alo[i] = f2bf(xv[i] - bf2f(h));
    }

    facc4 accq[8], acck[8];
    #pragma unroll
    for (int ct = 0; ct < 8; ++ct) {
      facc4 z = (facc4){0.f, 0.f, 0.f, 0.f};
      bfrag8 bq = *(const bfrag8*)(&Ws[(((0 * 8 + ct) * 4 + g) * 16 + lr) * 8]);
      facc4 aq = __builtin_amdgcn_mfma_f32_16x16x32_bf16(alo, bq, z, 0, 0, 0);
      accq[ct]  = __builtin_amdgcn_mfma_f32_16x16x32_bf16(ahi, bq, aq, 0, 0, 0);
      bfrag8 bk = *(const bfrag8*)(&Ws[(((1 * 8 + ct) * 4 + g) * 16 + lr) * 8]);
      facc4 ak = __builtin_amdgcn_mfma_f32_16x16x32_bf16(alo, bk, z, 0, 0, 0);
      acck[ct]  = __builtin_amdgcn_mfma_f32_16x16x32_bf16(ahi, bk, ak, 0, 0, 0);
    }

    #pragma unroll
    for (int h = 0; h < 8; ++h) {
      float s[4];
      #pragma unroll
      for (int r = 0; r < 4; ++r) {
        float qv = accq[h][r] + bq_l[h];
        float kv = acck[h][r] + bk_l[h];
        float p = qv * kv;
        p += __shfl_xor(p, 1, 16);
        p += __shfl_xor(p, 2, 16);
        p += __shfl_xor(p, 4, 16);
        p += __shfl_xor(p, 8, 16);
        s[r] = p;
      }
      if (lr == h) {
        #pragma unroll
        for (int r = 0; r < 4; ++r) {
          int e = e0 + g * 4 + r;
          if (e < E) ts[(size_t)e * 8 + h] = s[r];
        }
      }
    }
  }
}

// ---------------------------------------------------------------------------
// CSR build
// ---------------------------------------------------------------------------
__global__ __launch_bounds__(256) void count_deg_k(const int* __restrict__ tgt,
                                                   int* __restrict__ deg, int E) {
  int gid = blockIdx.x * 256 + threadIdx.x;
  if (gid < E) atomicAdd(&deg[tgt[gid]], 1);
}

__global__ __launch_bounds__(256) void block_sum_k(const int* __restrict__ deg,
                                                   int* __restrict__ bsum, int n) {
  __shared__ int sd[256];
  const int base = blockIdx.x * 1024;
  const int t = threadIdx.x;
  int s = 0;
  #pragma unroll
  for (int j = 0; j < 4; ++j) {
    int i = base + t + j * 256;
    if (i < n) s += deg[i];
  }
  sd[t] = s;
  __syncthreads();
  for (int st = 128; st; st >>= 1) {
    if (t < st) sd[t] += sd[t + st];
    __syncthreads();
  }
  if (t == 0) bsum[blockIdx.x] = sd[0];
}

__global__ __launch_bounds__(1024) void scan_partials_k(const int* __restrict__ bsum,
                                                        int* __restrict__ boff, int G) {
  __shared__ int sd[1024];
  const int t = threadIdx.x;
  int v = (t < G) ? bsum[t] : 0;
  sd[t] = v;
  __syncthreads();
  for (int s = 1; s < 1024; s <<= 1) {
    int a = (t >= s) ? sd[t - s] : 0;
    __syncthreads();
    sd[t] += a;
    __syncthreads();
  }
  if (t < G) boff[t] = sd[t] - v;
}

__global__ __launch_bounds__(256) void block_scan_k(const int* __restrict__ deg,
                                                    const int* __restrict__ boff,
                                                    int* __restrict__ off, int n) {
  __shared__ int sd[256];
  const int base = blockIdx.x * 1024;
  const int t = threadIdx.x;
  const int i0 = base + t * 4;
  int v[4];
  int s = 0;
  #pragma unroll
  for (int j = 0; j < 4; ++j) {
    v[j] = (i0 + j < n) ? deg[i0 + j] : 0;
    s += v[j];
  }
  const int own = s;
  sd[t] = s;
  __syncthreads();
  for (int st = 1; st < 256; st <<= 1) {
    int a = (t >= st) ? sd[t - st] : 0;
    __syncthreads();
    sd[t] += a;
    __syncthreads();
  }
  int acc = boff[blockIdx.x] + sd[t] - own;
  #pragma unroll
  for (int j = 0; j < 4; ++j) {
    int idx = i0 + j;
    if (idx < n) {
      off[idx] = acc;
      acc += v[j];
      if (idx == n - 1) off[n] = acc;
    }
  }
}

__global__ __launch_bounds__(256) void scatter_k(const int* __restrict__ tgt,
                                                 const int* __restrict__ off,
                                                 int* __restrict__ cur,
                                                 int* __restrict__ elist, int E) {
  int gid = blockIdx.x * 256 + threadIdx.x;
  if (gid < E) {
    int n = tgt[gid];
    int p = atomicAdd(&cur[n], 1);
    elist[off[n] + p] = gid;
  }
}

// ---------------------------------------------------------------------------
// Per-node QK score + segment softmax + aggregation.
// 32 lanes per node, lane g owns features g*4..g*4+3 (head h=g>>2, sub j=g&3).
// 8 nodes per 256-thread block; NO __syncthreads (per-group LDS slices,
// same-wave LDS ordering). Q/K/V bf16, 8B/lane gathers. agg stored bf16.
// ---------------------------------------------------------------------------
__global__ __launch_bounds__(256) void softmax_agg_k(
    const float* __restrict__ tscores, const short* __restrict__ Qp,
    const short* __restrict__ Kp, const short* __restrict__ Vp,
    const int* __restrict__ src, const int* __restrict__ off,
    const int* __restrict__ elist, float* __restrict__ attn_w,
    short* __restrict__ aggb, int N) {
  __shared__ int esh[8][MAXD];
  __shared__ int ssh[8][MAXD];
  __shared__ float sc[8][MAXD][8];
  const int t = threadIdx.x;
  const int grp = t >> 5;
  const int g = t & 31;
  const int h = g >> 2;
  const int j = g & 3;
  const int n = blockIdx.x * 8 + grp;
  if (n >= N) return;

  const int s0 = off[n];
  const int deg = off[n + 1] - s0;

  // K row fragment (4 features) in regs
  float kr[4];
  {
    bf4 k4 = *(const bf4*)(Kp + (size_t)n * HID + g * 4);
    #pragma unroll
    for (int q = 0; q < 4; ++q) kr[q] = bf2f(k4[q]);
  }

  if (deg <= MAXD) {
    for (int i = g; i < deg; i += 32) {
      int e = elist[s0 + i];
      esh[grp][i] = e;
      ssh[grp][i] = src[e];
    }
    // scores: sc[i][h] = tscores[e,h] + dot16(Q[src],K[n])/4, 2-wide unroll
    int i = 0;
    for (; i + 2 <= deg; i += 2) {
      int sn0 = ssh[grp][i], sn1 = ssh[grp][i + 1];
      int e0 = esh[grp][i], e1 = esh[grp][i + 1];
      bf4 q0 = *(const bf4*)(Qp + (size_t)sn0 * HID + g * 4);
      bf4 q1 = *(const bf4*)(Qp + (size_t)sn1 * HID + g * 4);
      float ts0 = tscores[(size_t)e0 * 8 + h];
      float ts1 = tscores[(size_t)e1 * 8 + h];
      float p0 = bf2f(q0[0]) * kr[0] + bf2f(q0[1]) * kr[1] +
                 bf2f(q0[2]) * kr[2] + bf2f(q0[3]) * kr[3];
      float p1 = bf2f(q1[0]) * kr[0] + bf2f(q1[1]) * kr[1] +
                 bf2f(q1[2]) * kr[2] + bf2f(q1[3]) * kr[3];
      p0 += __shfl_xor(p0, 1, 4); p0 += __shfl_xor(p0, 2, 4);
      p1 += __shfl_xor(p1, 1, 4); p1 += __shfl_xor(p1, 2, 4);
      if (j == 0) {
        sc[grp][i][h] = ts0 + p0 * 0.25f;
        sc[grp][i + 1][h] = ts1 + p1 * 0.25f;
      }
    }
    if (i < deg) {
      int sn0 = ssh[grp][i], e0 = esh[grp][i];
      bf4 q0 = *(const bf4*)(Qp + (size_t)sn0 * HID + g * 4);
      float ts0 = tscores[(size_t)e0 * 8 + h];
      float p0 = bf2f(q0[0]) * kr[0] + bf2f(q0[1]) * kr[1] +
                 bf2f(q0[2]) * kr[2] + bf2f(q0[3]) * kr[3];
      p0 += __shfl_xor(p0, 1, 4); p0 += __shfl_xor(p0, 2, 4);
      if (j == 0) sc[grp][i][h] = ts0 + p0 * 0.25f;
    }

    // max over edges for head h (lane j strides 4)
    float m = -3.0e38f;
    for (int q = j; q < deg; q += 4) m = fmaxf(m, sc[grp][q][h]);
    m = fmaxf(m, __shfl_xor(m, 1, 4));
    m = fmaxf(m, __shfl_xor(m, 2, 4));
    // exp + sum
    float l = 0.f;
    for (int q = j; q < deg; q += 4) {
      float e = __expf(sc[grp][q][h] - m);
      sc[grp][q][h] = e;
      l += e;
    }
    l += __shfl_xor(l, 1, 4);
    l += __shfl_xor(l, 2, 4);
    float invl = (l > 0.f) ? 1.0f / l : 0.f;

    // aggregation, 2-wide unroll
    float a0 = 0.f, a1 = 0.f, a2 = 0.f, a3 = 0.f;
    i = 0;
    for (; i + 2 <= deg; i += 2) {
      float w0 = sc[grp][i][h] * invl;
      float w1 = sc[grp][i + 1][h] * invl;
      bf4 v0 = *(const bf4*)(Vp + (size_t)ssh[grp][i] * HID + g * 4);
      bf4 v1 = *(const bf4*)(Vp + (size_t)ssh[grp][i + 1] * HID + g * 4);
      a0 += w0 * bf2f(v0[0]) + w1 * bf2f(v1[0]);
      a1 += w0 * bf2f(v0[1]) + w1 * bf2f(v1[1]);
      a2 += w0 * bf2f(v0[2]) + w1 * bf2f(v1[2]);
      a3 += w0 * bf2f(v0[3]) + w1 * bf2f(v1[3]);
      if (j == 0) {
        attn_w[(size_t)esh[grp][i] * 8 + h] = w0;
        attn_w[(size_t)esh[grp][i + 1] * 8 + h] = w1;
      }
    }
    if (i < deg) {
      float w0 = sc[grp][i][h] * invl;
      bf4 v0 = *(const bf4*)(Vp + (size_t)ssh[grp][i] * HID + g * 4);
      a0 += w0 * bf2f(v0[0]);
      a1 += w0 * bf2f(v0[1]);
      a2 += w0 * bf2f(v0[2]);
      a3 += w0 * bf2f(v0[3]);
      if (j == 0) attn_w[(size_t)esh[grp][i] * 8 + h] = w0;
    }
    bf4 st;
    st[0] = f2bf(a0); st[1] = f2bf(a1); st[2] = f2bf(a2); st[3] = f2bf(a3);
    *(bf4*)(aggb + (size_t)n * HID + g * 4) = st;
  } else {
    // fallback (deg > MAXD): 3-pass unstaged
    float m = -3.0e38f;
    for (int q = 0; q < deg; ++q) {
      int e = elist[s0 + q];
      bf4 q4 = *(const bf4*)(Qp + (size_t)src[e] * HID + g * 4);
      float p = bf2f(q4[0]) * kr[0] + bf2f(q4[1]) * kr[1] +
                bf2f(q4[2]) * kr[2] + bf2f(q4[3]) * kr[3];
      p += __shfl_xor(p, 1, 4); p += __shfl_xor(p, 2, 4);
      m = fmaxf(m, tscores[(size_t)e * 8 + h] + p * 0.25f);
    }
    float l = 0.f;
    for (int q = 0; q < deg; ++q) {
      int e = elist[s0 + q];
      bf4 q4 = *(const bf4*)(Qp + (size_t)src[e] * HID + g * 4);
      float p = bf2f(q4[0]) * kr[0] + bf2f(q4[1]) * kr[1] +
                bf2f(q4[2]) * kr[2] + bf2f(q4[3]) * kr[3];
      p += __shfl_xor(p, 1, 4); p += __shfl_xor(p, 2, 4);
      l += __expf(tscores[(size_t)e * 8 + h] + p * 0.25f - m);
    }
    float invl = (l > 0.f) ? 1.0f / l : 0.f;
    float a0 = 0.f, a1 = 0.f, a2 = 0.f, a3 = 0.f;
    for (int q = 0; q < deg; ++q) {
      int e = elist[s0 + q];
      int sn = src[e];
      bf4 q4 = *(const bf4*)(Qp + (size_t)sn * HID + g * 4);
      float p = bf2f(q4[0]) * kr[0] + bf2f(q4[1]) * kr[1] +
                bf2f(q4[2]) * kr[2] + bf2f(q4[3]) * kr[3];
      p += __shfl_xor(p, 1, 4); p += __shfl_xor(p, 2, 4);
      float w = __expf(tscores[(size_t)e * 8 + h] + p * 0.25f - m) * invl;
      bf4 v4 = *(const bf4*)(Vp + (size_t)sn * HID + g * 4);
      a0 += w * bf2f(v4[0]);
      a1 += w * bf2f(v4[1]);
      a2 += w * bf2f(v4[2]);
      a3 += w * bf2f(v4[3]);
      if (j == 0) attn_w[(size_t)e * 8 + h] = w;
    }
    bf4 st;
    st[0] = f2bf(a0); st[1] = f2bf(a1); st[2] = f2bf(a2); st[3] = f2bf(a3);
    *(bf4*)(aggb + (size_t)n * HID + g * 4) = st;
  }
}

// ---------------------------------------------------------------------------
extern "C" void kernel_launch(void* const* d_in, const int* in_sizes, int n_in,
                              void* d_out, int out_size, void* d_ws, size_t ws_size,
                              hipStream_t stream) {
  const float* query    = (const float*)d_in[0];
  const float* key      = (const float*)d_in[1];
  const float* value    = (const float*)d_in[2];
  const float* temporal = (const float*)d_in[3];
  const int*   eidx     = (const int*)d_in[4];
  const float* Wq   = (const float*)d_in[5];
  const float* bq   = (const float*)d_in[6];
  const float* Wk   = (const float*)d_in[7];
  const float* bk   = (const float*)d_in[8];
  const float* Wv   = (const float*)d_in[9];
  const float* bv   = (const float*)d_in[10];
  const float* Wtq  = (const float*)d_in[11];
  const float* btq  = (const float*)d_in[12];
  const float* Wtk  = (const float*)d_in[13];
  const float* btk  = (const float*)d_in[14];
  const float* Wout = (const float*)d_in[15];
  const float* bout = (const float*)d_in[16];

  const int N = in_sizes[0] / HID;
  const int E = in_sizes[4] / 2;
  const int* src = eidx;
  const int* tgt = eidx + E;

  char* ws = (char*)d_ws;
  short* Qp = (short*)ws;                      ws += (size_t)N * HID * 2;
  short* Kp = (short*)ws;                      ws += (size_t)N * HID * 2;
  short* Vp = (short*)ws;                      ws += (size_t)N * HID * 2;
  short* aggb = (short*)ws;                    ws += (size_t)N * HID * 2;
  float* tscores = (float*)ws;                 ws += (size_t)E * 8 * 4;
  int* deg   = (int*)ws;                       ws += (size_t)N * 4;
  int* cur   = (int*)ws;                       ws += (size_t)N * 4;
  int* off   = (int*)ws;                       ws += (size_t)(N + 1) * 4;
  int* elist = (int*)ws;                       ws += (size_t)E * 4;
  int* bsum  = (int*)ws;                       ws += 1024 * 4;
  int* boff  = (int*)ws;

  const int G = (N + 1023) / 1024;

  hipMemsetAsync(deg, 0, sizeof(int) * 2 * (size_t)N, stream);  // deg + cur

  dim3 b256(256);
  const int gblk = (N + 63) / 64;
  gemm_mfma_k<float, short><<<gblk, b256, 0, stream>>>(query, Wq, bq, Qp, N);
  gemm_mfma_k<float, short><<<gblk, b256, 0, stream>>>(key,   Wk, bk, Kp, N);
  gemm_mfma_k<float, short><<<gblk, b256, 0, stream>>>(value, Wv, bv, Vp, N);

  temporal_mfma_k<<<2048, b256, 0, stream>>>(temporal, Wtq, Wtk, btq, btk,
                                             tscores, E, (E + 63) / 64);

  count_deg_k<<<(E + 255) / 256, b256, 0, stream>>>(tgt, deg, E);
  block_sum_k<<<G, b256, 0, stream>>>(deg, bsum, N);
  scan_partials_k<<<1, 1024, 0, stream>>>(bsum, boff, G);
  block_scan_k<<<G, b256, 0, stream>>>(deg, boff, off, N);
  scatter_k<<<(E + 255) / 256, b256, 0, stream>>>(tgt, off, cur, elist, E);

  float* attn_w = (float*)d_out + (size_t)N * HID;
  softmax_agg_k<<<(N + 7) / 8, b256, 0, stream>>>(tscores, Qp, Kp, Vp, src, off,
                                                  elist, attn_w, aggb, N);

  gemm_mfma_k<short, float><<<gblk, b256, 0, stream>>>(aggb, Wout, bout,
                                                       (float*)d_out, N);
}

// Round 5
// 346.859 us; speedup vs baseline: 2.6158x; 1.0481x over previous
//
#include <hip/hip_runtime.h>
#include <hip/hip_bf16.h>

#define HID 128
#define MAXD 64  // per-node fast-path degree cap (Poisson(6) max ~25)

typedef __attribute__((ext_vector_type(8))) short bfrag8;
typedef __attribute__((ext_vector_type(4))) short bf4;
typedef __attribute__((ext_vector_type(4))) float facc4;

// f32 -> bf16 bits, round-to-nearest-even
__device__ inline short f2bf(float x) {
  unsigned u = __builtin_bit_cast(unsigned, x);
  u += 0x7fffu + ((u >> 16) & 1u);
  return (short)(u >> 16);
}
__device__ inline float bf2f(short s) {
  unsigned u = ((unsigned)(unsigned short)s) << 16;
  return __builtin_bit_cast(float, u);
}

__device__ inline void store_out(float* Y, size_t i, float v) { Y[i] = v; }
__device__ inline void store_out(short* Y, size_t i, float v) { Y[i] = f2bf(v); }

// ---------------------------------------------------------------------------
// Y[r,c] = X[r,:128] @ W[:128,c] + b[c] via bf16 MFMA.
// IT=float: split-X (hi+lo, 2 MFMA). IT=short(bf16): direct (1 MFMA).
// Block 256 (4 waves), 64 rows/block. W staged once in LDS as fragment-linear
// bf16 chunks: [ct 8][kt 4][g 4][c 16] x 16B.
// ---------------------------------------------------------------------------
template <typename IT, typename OT>
__global__ __launch_bounds__(256) void gemm_mfma_k(
    const IT* __restrict__ X, const float* __restrict__ W,
    const float* __restrict__ b, OT* __restrict__ Y, int nrows) {
  __shared__ short Ws[8 * 4 * 4 * 16 * 8];  // 32KB
  const int t = threadIdx.x;

  #pragma unroll
  for (int it = 0; it < 8; ++it) {
    int chunk = t + it * 256;  // 2048 chunks
    int c  = chunk & 15;
    int g  = (chunk >> 4) & 3;
    int kt = (chunk >> 6) & 3;
    int ct = chunk >> 8;
    int col = ct * 16 + c;
    int k0 = kt * 32 + g * 8;
    bfrag8 v;
    #pragma unroll
    for (int i = 0; i < 8; ++i) v[i] = f2bf(W[(size_t)(k0 + i) * HID + col]);
    *(bfrag8*)(&Ws[chunk * 8]) = v;
  }
  __syncthreads();

  const int w  = t >> 6;
  const int l  = t & 63;
  const int lr = l & 15;
  const int g  = l >> 4;
  const int row0 = blockIdx.x * 64 + w * 16;
  const int arow = min(row0 + lr, nrows - 1);

  facc4 acc[8];
  #pragma unroll
  for (int i = 0; i < 8; ++i) acc[i] = (facc4){0.f, 0.f, 0.f, 0.f};

  #pragma unroll
  for (int kt = 0; kt < 4; ++kt) {
    if constexpr (sizeof(IT) == 4) {
      const float* xp = (const float*)X + (size_t)arow * HID + kt * 32 + g * 8;
      float xv[8];
      *(facc4*)(xv)     = *(const facc4*)(xp);
      *(facc4*)(xv + 4) = *(const facc4*)(xp + 4);
      bfrag8 ahi, alo;
      #pragma unroll
      for (int i = 0; i < 8; ++i) {
        short h = f2bf(xv[i]);
        ahi[i] = h;
        alo[i] = f2bf(xv[i] - bf2f(h));
      }
      #pragma unroll
      for (int ct = 0; ct < 8; ++ct) {
        bfrag8 bf = *(const bfrag8*)(&Ws[(((ct * 4 + kt) * 4 + g) * 16 + lr) * 8]);
        acc[ct] = __builtin_amdgcn_mfma_f32_16x16x32_bf16(alo, bf, acc[ct], 0, 0, 0);
        acc[ct] = __builtin_amdgcn_mfma_f32_16x16x32_bf16(ahi, bf, acc[ct], 0, 0, 0);
      }
    } else {
      bfrag8 a = *(const bfrag8*)((const short*)X + (size_t)arow * HID + kt * 32 + g * 8);
      #pragma unroll
      for (int ct = 0; ct < 8; ++ct) {
        bfrag8 bf = *(const bfrag8*)(&Ws[(((ct * 4 + kt) * 4 + g) * 16 + lr) * 8]);
        acc[ct] = __builtin_amdgcn_mfma_f32_16x16x32_bf16(a, bf, acc[ct], 0, 0, 0);
      }
    }
  }

  #pragma unroll
  for (int ct = 0; ct < 8; ++ct) {
    int col = ct * 16 + lr;
    float bias = b[col];
    #pragma unroll
    for (int r = 0; r < 4; ++r) {
      int row = row0 + g * 4 + r;
      if (row < nrows)
        store_out(Y, (size_t)row * HID + col, acc[ct][r] + bias);
    }
  }
}

// ---------------------------------------------------------------------------
// Temporal scores via MFMA (split-T), persistent grid, 64 edges/block.
// Low-VGPR: one head (ct) at a time, bias folded into accumulator init.
// ---------------------------------------------------------------------------
__global__ __launch_bounds__(256) void temporal_mfma_k(
    const float* __restrict__ T, const float* __restrict__ Wtq,
    const float* __restrict__ Wtk, const float* __restrict__ btq,
    const float* __restrict__ btk, float* __restrict__ ts, int E, int ntiles) {
  __shared__ short Ws[2 * 8 * 4 * 16 * 8];  // 16KB
  const int t = threadIdx.x;

  #pragma unroll
  for (int it = 0; it < 4; ++it) {
    int chunk = t + it * 256;
    int c  = chunk & 15;
    int g  = (chunk >> 4) & 3;
    int ct = (chunk >> 6) & 7;
    int qk = chunk >> 9;
    const float* Wsrc = qk ? Wtk : Wtq;
    int col = ct * 16 + c;
    int k0 = g * 8;
    bfrag8 v;
    #pragma unroll
    for (int i = 0; i < 8; ++i) v[i] = f2bf(Wsrc[(size_t)(k0 + i) * HID + col]);
    *(bfrag8*)(&Ws[chunk * 8]) = v;
  }
  __syncthreads();

  const int w  = t >> 6;
  const int l  = t & 63;
  const int lr = l & 15;
  const int g  = l >> 4;
  float bq_l[8], bk_l[8];
  #pragma unroll
  for (int h = 0; h < 8; ++h) {
    bq_l[h] = btq[h * 16 + lr];
    bk_l[h] = btk[h * 16 + lr];
  }

  for (int tile = blockIdx.x; tile < ntiles; tile += gridDim.x) {
    const int e0 = tile * 64 + w * 16;
    const int ar = min(e0 + lr, E - 1);
    const float* tp = T + (size_t)ar * 32 + g * 8;
    float xv[8];
    *(facc4*)(xv)     = *(const facc4*)(tp);
    *(facc4*)(xv + 4) = *(const facc4*)(tp + 4);
    bfrag8 ahi, alo;
    #pragma unroll
    for (int i = 0; i < 8; ++i) {
      short h = f2bf(xv[i]);
      ahi[i] = h;
      alo[i] = f2bf(xv[i] - bf2f(h));
    }
    const bool full = (e0 + 15 < E);

    #pragma unroll
    for (int ct = 0; ct < 8; ++ct) {
      // bias folded into C-in
      facc4 accq = (facc4){bq_l[ct], bq_l[ct], bq_l[ct], bq_l[ct]};
      bfrag8 bqf = *(const bfrag8*)(&Ws[(((0 * 8 + ct) * 4 + g) * 16 + lr) * 8]);
      accq = __builtin_amdgcn_mfma_f32_16x16x32_bf16(alo, bqf, accq, 0, 0, 0);
      accq = __builtin_amdgcn_mfma_f32_16x16x32_bf16(ahi, bqf, accq, 0, 0, 0);
      facc4 acck = (facc4){bk_l[ct], bk_l[ct], bk_l[ct], bk_l[ct]};
      bfrag8 bkf = *(const bfrag8*)(&Ws[(((1 * 8 + ct) * 4 + g) * 16 + lr) * 8]);
      acck = __builtin_amdgcn_mfma_f32_16x16x32_bf16(alo, bkf, acck, 0, 0, 0);
      acck = __builtin_amdgcn_mfma_f32_16x16x32_bf16(ahi, bkf, acck, 0, 0, 0);

      float p[4];
      #pragma unroll
      for (int r = 0; r < 4; ++r) {
        float v = accq[r] * acck[r];
        v += __shfl_xor(v, 1, 16);
        v += __shfl_xor(v, 2, 16);
        v += __shfl_xor(v, 4, 16);
        v += __shfl_xor(v, 8, 16);
        p[r] = v;
      }
      if (lr == ct) {
        if (full) {
          #pragma unroll
          for (int r = 0; r < 4; ++r)
            ts[(size_t)(e0 + g * 4 + r) * 8 + ct] = p[r];
        } else {
          #pragma unroll
          for (int r = 0; r < 4; ++r) {
            int e = e0 + g * 4 + r;
            if (e < E) ts[(size_t)e * 8 + ct] = p[r];
          }
        }
      }
    }
  }
}

// ---------------------------------------------------------------------------
// CSR build
// ---------------------------------------------------------------------------
__global__ __launch_bounds__(256) void count_deg_k(const int* __restrict__ tgt,
                                                   int* __restrict__ deg, int E) {
  int gid = blockIdx.x * 256 + threadIdx.x;
  if (gid < E) atomicAdd(&deg[tgt[gid]], 1);
}

__global__ __launch_bounds__(256) void block_sum_k(const int* __restrict__ deg,
                                                   int* __restrict__ bsum, int n) {
  __shared__ int sd[256];
  const int base = blockIdx.x * 1024;
  const int t = threadIdx.x;
  int s = 0;
  #pragma unroll
  for (int j = 0; j < 4; ++j) {
    int i = base + t + j * 256;
    if (i < n) s += deg[i];
  }
  sd[t] = s;
  __syncthreads();
  for (int st = 128; st; st >>= 1) {
    if (t < st) sd[t] += sd[t + st];
    __syncthreads();
  }
  if (t == 0) bsum[blockIdx.x] = sd[0];
}

__global__ __launch_bounds__(1024) void scan_partials_k(const int* __restrict__ bsum,
                                                        int* __restrict__ boff, int G) {
  __shared__ int sd[1024];
  const int t = threadIdx.x;
  int v = (t < G) ? bsum[t] : 0;
  sd[t] = v;
  __syncthreads();
  for (int s = 1; s < 1024; s <<= 1) {
    int a = (t >= s) ? sd[t - s] : 0;
    __syncthreads();
    sd[t] += a;
    __syncthreads();
  }
  if (t < G) boff[t] = sd[t] - v;
}

__global__ __launch_bounds__(256) void block_scan_k(const int* __restrict__ deg,
                                                    const int* __restrict__ boff,
                                                    int* __restrict__ off, int n) {
  __shared__ int sd[256];
  const int base = blockIdx.x * 1024;
  const int t = threadIdx.x;
  const int i0 = base + t * 4;
  int v[4];
  int s = 0;
  #pragma unroll
  for (int j = 0; j < 4; ++j) {
    v[j] = (i0 + j < n) ? deg[i0 + j] : 0;
    s += v[j];
  }
  const int own = s;
  sd[t] = s;
  __syncthreads();
  for (int st = 1; st < 256; st <<= 1) {
    int a = (t >= st) ? sd[t - st] : 0;
    __syncthreads();
    sd[t] += a;
    __syncthreads();
  }
  int acc = boff[blockIdx.x] + sd[t] - own;
  #pragma unroll
  for (int j = 0; j < 4; ++j) {
    int idx = i0 + j;
    if (idx < n) {
      off[idx] = acc;
      acc += v[j];
      if (idx == n - 1) off[n] = acc;
    }
  }
}

__global__ __launch_bounds__(256) void scatter_k(const int* __restrict__ tgt,
                                                 const int* __restrict__ off,
                                                 int* __restrict__ cur,
                                                 int* __restrict__ elist, int E) {
  int gid = blockIdx.x * 256 + threadIdx.x;
  if (gid < E) {
    int n = tgt[gid];
    int p = atomicAdd(&cur[n], 1);
    elist[off[n] + p] = gid;
  }
}

// ---------------------------------------------------------------------------
// Per-node QK score + ONLINE softmax + aggregation in ONE gather pass.
// 32 lanes per node, lane g owns features g*4..g*4+3 (head h=g>>2, sub j=g&3).
// 8 nodes per 256-thread block; NO __syncthreads (per-group LDS slices,
// same-wave LDS ordering). Q/K/V bf16, 8B/lane gathers. agg stored bf16.
// ---------------------------------------------------------------------------
__global__ __launch_bounds__(256) void softmax_agg_k(
    const float* __restrict__ tscores, const short* __restrict__ Qp,
    const short* __restrict__ Kp, const short* __restrict__ Vp,
    const int* __restrict__ src, const int* __restrict__ off,
    const int* __restrict__ elist, float* __restrict__ attn_w,
    short* __restrict__ aggb, int N) {
  __shared__ int esh[8][MAXD];
  __shared__ int ssh[8][MAXD];
  __shared__ float sraw[8][MAXD][8];  // raw scores per head
  const int t = threadIdx.x;
  const int grp = t >> 5;
  const int g = t & 31;
  const int h = g >> 2;
  const int j = g & 3;
  const int n = blockIdx.x * 8 + grp;
  if (n >= N) return;

  const int s0 = off[n];
  const int deg = off[n + 1] - s0;

  float kr[4];
  {
    bf4 k4 = *(const bf4*)(Kp + (size_t)n * HID + g * 4);
    #pragma unroll
    for (int q = 0; q < 4; ++q) kr[q] = bf2f(k4[q]);
  }

  if (deg <= MAXD) {
    for (int i = g; i < deg; i += 32) {
      int e = elist[s0 + i];
      esh[grp][i] = e;
      ssh[grp][i] = src[e];
    }

    // single online pass: score + max + exp-sum + unnormalized aggregation
    float m = -3.0e38f, lsum = 0.f;
    float a0 = 0.f, a1 = 0.f, a2 = 0.f, a3 = 0.f;
    int i = 0;
    for (; i + 2 <= deg; i += 2) {
      int sn0 = ssh[grp][i], sn1 = ssh[grp][i + 1];
      int e0 = esh[grp][i], e1 = esh[grp][i + 1];
      bf4 q0 = *(const bf4*)(Qp + (size_t)sn0 * HID + g * 4);
      bf4 q1 = *(const bf4*)(Qp + (size_t)sn1 * HID + g * 4);
      bf4 v0 = *(const bf4*)(Vp + (size_t)sn0 * HID + g * 4);
      bf4 v1 = *(const bf4*)(Vp + (size_t)sn1 * HID + g * 4);
      float ts0 = tscores[(size_t)e0 * 8 + h];
      float ts1 = tscores[(size_t)e1 * 8 + h];
      float p0 = bf2f(q0[0]) * kr[0] + bf2f(q0[1]) * kr[1] +
                 bf2f(q0[2]) * kr[2] + bf2f(q0[3]) * kr[3];
      float p1 = bf2f(q1[0]) * kr[0] + bf2f(q1[1]) * kr[1] +
                 bf2f(q1[2]) * kr[2] + bf2f(q1[3]) * kr[3];
      p0 += __shfl_xor(p0, 1, 4); p0 += __shfl_xor(p0, 2, 4);
      p1 += __shfl_xor(p1, 1, 4); p1 += __shfl_xor(p1, 2, 4);
      float sc0 = ts0 + p0 * 0.25f;
      float sc1 = ts1 + p1 * 0.25f;
      if (j == 0) {
        sraw[grp][i][h] = sc0;
        sraw[grp][i + 1][h] = sc1;
      }
      float newm = fmaxf(fmaxf(m, sc0), sc1);
      float scale = __expf(m - newm);
      float w0 = __expf(sc0 - newm);
      float w1 = __expf(sc1 - newm);
      lsum = lsum * scale + w0 + w1;
      a0 = a0 * scale + w0 * bf2f(v0[0]) + w1 * bf2f(v1[0]);
      a1 = a1 * scale + w0 * bf2f(v0[1]) + w1 * bf2f(v1[1]);
      a2 = a2 * scale + w0 * bf2f(v0[2]) + w1 * bf2f(v1[2]);
      a3 = a3 * scale + w0 * bf2f(v0[3]) + w1 * bf2f(v1[3]);
      m = newm;
    }
    if (i < deg) {
      int sn0 = ssh[grp][i], e0 = esh[grp][i];
      bf4 q0 = *(const bf4*)(Qp + (size_t)sn0 * HID + g * 4);
      bf4 v0 = *(const bf4*)(Vp + (size_t)sn0 * HID + g * 4);
      float ts0 = tscores[(size_t)e0 * 8 + h];
      float p0 = bf2f(q0[0]) * kr[0] + bf2f(q0[1]) * kr[1] +
                 bf2f(q0[2]) * kr[2] + bf2f(q0[3]) * kr[3];
      p0 += __shfl_xor(p0, 1, 4); p0 += __shfl_xor(p0, 2, 4);
      float sc0 = ts0 + p0 * 0.25f;
      if (j == 0) sraw[grp][i][h] = sc0;
      float newm = fmaxf(m, sc0);
      float scale = __expf(m - newm);
      float w0 = __expf(sc0 - newm);
      lsum = lsum * scale + w0;
      a0 = a0 * scale + w0 * bf2f(v0[0]);
      a1 = a1 * scale + w0 * bf2f(v0[1]);
      a2 = a2 * scale + w0 * bf2f(v0[2]);
      a3 = a3 * scale + w0 * bf2f(v0[3]);
      m = newm;
    }
    float invl = (lsum > 0.f) ? 1.0f / lsum : 0.f;

    bf4 st;
    st[0] = f2bf(a0 * invl); st[1] = f2bf(a1 * invl);
    st[2] = f2bf(a2 * invl); st[3] = f2bf(a3 * invl);
    *(bf4*)(aggb + (size_t)n * HID + g * 4) = st;

    // attn_w tail: gather-free, j==0 lanes only
    if (j == 0) {
      for (int q = 0; q < deg; ++q) {
        float w = __expf(sraw[grp][q][h] - m) * invl;
        attn_w[(size_t)esh[grp][q] * 8 + h] = w;
      }
    }
  } else {
    // fallback (deg > MAXD): 3-pass unstaged
    float m = -3.0e38f;
    for (int q = 0; q < deg; ++q) {
      int e = elist[s0 + q];
      bf4 q4 = *(const bf4*)(Qp + (size_t)src[e] * HID + g * 4);
      float p = bf2f(q4[0]) * kr[0] + bf2f(q4[1]) * kr[1] +
                bf2f(q4[2]) * kr[2] + bf2f(q4[3]) * kr[3];
      p += __shfl_xor(p, 1, 4); p += __shfl_xor(p, 2, 4);
      m = fmaxf(m, tscores[(size_t)e * 8 + h] + p * 0.25f);
    }
    float l = 0.f;
    for (int q = 0; q < deg; ++q) {
      int e = elist[s0 + q];
      bf4 q4 = *(const bf4*)(Qp + (size_t)src[e] * HID + g * 4);
      float p = bf2f(q4[0]) * kr[0] + bf2f(q4[1]) * kr[1] +
                bf2f(q4[2]) * kr[2] + bf2f(q4[3]) * kr[3];
      p += __shfl_xor(p, 1, 4); p += __shfl_xor(p, 2, 4);
      l += __expf(tscores[(size_t)e * 8 + h] + p * 0.25f - m);
    }
    float invl = (l > 0.f) ? 1.0f / l : 0.f;
    float a0 = 0.f, a1 = 0.f, a2 = 0.f, a3 = 0.f;
    for (int q = 0; q < deg; ++q) {
      int e = elist[s0 + q];
      int sn = src[e];
      bf4 q4 = *(const bf4*)(Qp + (size_t)sn * HID + g * 4);
      float p = bf2f(q4[0]) * kr[0] + bf2f(q4[1]) * kr[1] +
                bf2f(q4[2]) * kr[2] + bf2f(q4[3]) * kr[3];
      p += __shfl_xor(p, 1, 4); p += __shfl_xor(p, 2, 4);
      float w = __expf(tscores[(size_t)e * 8 + h] + p * 0.25f - m) * invl;
      bf4 v4 = *(const bf4*)(Vp + (size_t)sn * HID + g * 4);
      a0 += w * bf2f(v4[0]);
      a1 += w * bf2f(v4[1]);
      a2 += w * bf2f(v4[2]);
      a3 += w * bf2f(v4[3]);
      if (j == 0) attn_w[(size_t)e * 8 + h] = w;
    }
    bf4 st;
    st[0] = f2bf(a0); st[1] = f2bf(a1); st[2] = f2bf(a2); st[3] = f2bf(a3);
    *(bf4*)(aggb + (size_t)n * HID + g * 4) = st;
  }
}

// ---------------------------------------------------------------------------
extern "C" void kernel_launch(void* const* d_in, const int* in_sizes, int n_in,
                              void* d_out, int out_size, void* d_ws, size_t ws_size,
                              hipStream_t stream) {
  const float* query    = (const float*)d_in[0];
  const float* key      = (const float*)d_in[1];
  const float* value    = (const float*)d_in[2];
  const float* temporal = (const float*)d_in[3];
  const int*   eidx     = (const int*)d_in[4];
  const float* Wq   = (const float*)d_in[5];
  const float* bq   = (const float*)d_in[6];
  const float* Wk   = (const float*)d_in[7];
  const float* bk   = (const float*)d_in[8];
  const float* Wv   = (const float*)d_in[9];
  const float* bv   = (const float*)d_in[10];
  const float* Wtq  = (const float*)d_in[11];
  const float* btq  = (const float*)d_in[12];
  const float* Wtk  = (const float*)d_in[13];
  const float* btk  = (const float*)d_in[14];
  const float* Wout = (const float*)d_in[15];
  const float* bout = (const float*)d_in[16];

  const int N = in_sizes[0] / HID;
  const int E = in_sizes[4] / 2;
  const int* src = eidx;
  const int* tgt = eidx + E;

  char* ws = (char*)d_ws;
  short* Qp = (short*)ws;                      ws += (size_t)N * HID * 2;
  short* Kp = (short*)ws;                      ws += (size_t)N * HID * 2;
  short* Vp = (short*)ws;                      ws += (size_t)N * HID * 2;
  short* aggb = (short*)ws;                    ws += (size_t)N * HID * 2;
  float* tscores = (float*)ws;                 ws += (size_t)E * 8 * 4;
  int* deg   = (int*)ws;                       ws += (size_t)N * 4;
  int* cur   = (int*)ws;                       ws += (size_t)N * 4;
  int* off   = (int*)ws;                       ws += (size_t)(N + 1) * 4;
  int* elist = (int*)ws;                       ws += (size_t)E * 4;
  int* bsum  = (int*)ws;                       ws += 1024 * 4;
  int* boff  = (int*)ws;

  const int G = (N + 1023) / 1024;

  hipMemsetAsync(deg, 0, sizeof(int) * 2 * (size_t)N, stream);  // deg + cur

  dim3 b256(256);
  const int gblk = (N + 63) / 64;
  gemm_mfma_k<float, short><<<gblk, b256, 0, stream>>>(query, Wq, bq, Qp, N);
  gemm_mfma_k<float, short><<<gblk, b256, 0, stream>>>(key,   Wk, bk, Kp, N);
  gemm_mfma_k<float, short><<<gblk, b256, 0, stream>>>(value, Wv, bv, Vp, N);

  temporal_mfma_k<<<2048, b256, 0, stream>>>(temporal, Wtq, Wtk, btq, btk,
                                             tscores, E, (E + 63) / 64);

  count_deg_k<<<(E + 255) / 256, b256, 0, stream>>>(tgt, deg, E);
  block_sum_k<<<G, b256, 0, stream>>>(deg, bsum, N);
  scan_partials_k<<<1, 1024, 0, stream>>>(bsum, boff, G);
  block_scan_k<<<G, b256, 0, stream>>>(deg, boff, off, N);
  scatter_k<<<(E + 255) / 256, b256, 0, stream>>>(tgt, off, cur, elist, E);

  float* attn_w = (float*)d_out + (size_t)N * HID;
  softmax_agg_k<<<(N + 7) / 8, b256, 0, stream>>>(tscores, Qp, Kp, Vp, src, off,
                                                  elist, attn_w, aggb, N);

  gemm_mfma_k<short, float><<<gblk, b256, 0, stream>>>(aggb, Wout, bout,
                                                       (float*)d_out, N);
}

// Round 6
// 315.118 us; speedup vs baseline: 2.8793x; 1.1007x over previous
//
#include <hip/hip_runtime.h>
#include <hip/hip_bf16.h>

#define HID 128
#define MAXD 64  // per-node fast-path degree cap (Poisson(6) max ~25)

typedef __attribute__((ext_vector_type(8))) short bfrag8;
typedef __attribute__((ext_vector_type(4))) short bf4;
typedef __attribute__((ext_vector_type(4))) float facc4;

// f32 -> bf16 bits, round-to-nearest-even
__device__ inline short f2bf(float x) {
  unsigned u = __builtin_bit_cast(unsigned, x);
  u += 0x7fffu + ((u >> 16) & 1u);
  return (short)(u >> 16);
}
__device__ inline float bf2f(short s) {
  unsigned u = ((unsigned)(unsigned short)s) << 16;
  return __builtin_bit_cast(float, u);
}

__device__ inline void store_out(float* Y, size_t i, float v) { Y[i] = v; }
__device__ inline void store_out(short* Y, size_t i, float v) { Y[i] = f2bf(v); }

// ---------------------------------------------------------------------------
// One-shot weight pre-format: f32 W -> fragment-linear bf16 chunks.
// Chunks 0..8191: Wq,Wk,Wv,Wout (2048 each), layout ct<<8|kt<<6|g<<4|c.
// Chunks 8192..9215: [Wtq|Wtk] (1024), layout qk<<9|ct<<6|g<<4|c.
// ---------------------------------------------------------------------------
__global__ __launch_bounds__(256) void preformat_k(
    const float* __restrict__ Wq, const float* __restrict__ Wk,
    const float* __restrict__ Wv, const float* __restrict__ Wout,
    const float* __restrict__ Wtq, const float* __restrict__ Wtk,
    short* __restrict__ out) {
  int gid = blockIdx.x * 256 + threadIdx.x;
  if (gid >= 9216) return;
  bfrag8 v;
  if (gid < 8192) {
    int which = gid >> 11;
    int chunk = gid & 2047;
    const float* W = (which == 0) ? Wq : (which == 1) ? Wk
                   : (which == 2) ? Wv : Wout;
    int c  = chunk & 15;
    int g  = (chunk >> 4) & 3;
    int kt = (chunk >> 6) & 3;
    int ct = chunk >> 8;
    int col = ct * 16 + c;
    int k0 = kt * 32 + g * 8;
    #pragma unroll
    for (int i = 0; i < 8; ++i) v[i] = f2bf(W[(size_t)(k0 + i) * HID + col]);
  } else {
    int chunk = gid - 8192;
    int c  = chunk & 15;
    int g  = (chunk >> 4) & 3;
    int ct = (chunk >> 6) & 7;
    int qk = chunk >> 9;
    const float* W = qk ? Wtk : Wtq;
    int col = ct * 16 + c;
    int k0 = g * 8;
    #pragma unroll
    for (int i = 0; i < 8; ++i) v[i] = f2bf(W[(size_t)(k0 + i) * HID + col]);
  }
  *(bfrag8*)(out + (size_t)gid * 8) = v;
}

// ---------------------------------------------------------------------------
// Y[r,c] = X[r,:128] @ W[:128,c] + b[c] via bf16 MFMA.
// IT=float: split-X (hi+lo, 2 MFMA). IT=short(bf16): direct (1 MFMA).
// W pre-formatted bf16 chunks; prologue is a pure 16B copy.
// ---------------------------------------------------------------------------
template <typename IT, typename OT>
__global__ __launch_bounds__(256) void gemm_mfma_k(
    const IT* __restrict__ X, const short* __restrict__ Wp,
    const float* __restrict__ b, OT* __restrict__ Y, int nrows) {
  __shared__ short Ws[8 * 4 * 4 * 16 * 8];  // 32KB
  const int t = threadIdx.x;

  #pragma unroll
  for (int it = 0; it < 8; ++it) {
    int chunk = t + it * 256;
    *(bfrag8*)(&Ws[chunk * 8]) = *(const bfrag8*)(Wp + (size_t)chunk * 8);
  }
  __syncthreads();

  const int w  = t >> 6;
  const int l  = t & 63;
  const int lr = l & 15;
  const int g  = l >> 4;
  const int row0 = blockIdx.x * 64 + w * 16;
  const int arow = min(row0 + lr, nrows - 1);

  facc4 acc[8];
  #pragma unroll
  for (int i = 0; i < 8; ++i) acc[i] = (facc4){0.f, 0.f, 0.f, 0.f};

  #pragma unroll
  for (int kt = 0; kt < 4; ++kt) {
    if constexpr (sizeof(IT) == 4) {
      const float* xp = (const float*)X + (size_t)arow * HID + kt * 32 + g * 8;
      float xv[8];
      *(facc4*)(xv)     = *(const facc4*)(xp);
      *(facc4*)(xv + 4) = *(const facc4*)(xp + 4);
      bfrag8 ahi, alo;
      #pragma unroll
      for (int i = 0; i < 8; ++i) {
        short h = f2bf(xv[i]);
        ahi[i] = h;
        alo[i] = f2bf(xv[i] - bf2f(h));
      }
      #pragma unroll
      for (int ct = 0; ct < 8; ++ct) {
        bfrag8 bf = *(const bfrag8*)(&Ws[(((ct * 4 + kt) * 4 + g) * 16 + lr) * 8]);
        acc[ct] = __builtin_amdgcn_mfma_f32_16x16x32_bf16(alo, bf, acc[ct], 0, 0, 0);
        acc[ct] = __builtin_amdgcn_mfma_f32_16x16x32_bf16(ahi, bf, acc[ct], 0, 0, 0);
      }
    } else {
      bfrag8 a = *(const bfrag8*)((const short*)X + (size_t)arow * HID + kt * 32 + g * 8);
      #pragma unroll
      for (int ct = 0; ct < 8; ++ct) {
        bfrag8 bf = *(const bfrag8*)(&Ws[(((ct * 4 + kt) * 4 + g) * 16 + lr) * 8]);
        acc[ct] = __builtin_amdgcn_mfma_f32_16x16x32_bf16(a, bf, acc[ct], 0, 0, 0);
      }
    }
  }

  #pragma unroll
  for (int ct = 0; ct < 8; ++ct) {
    int col = ct * 16 + lr;
    float bias = b[col];
    #pragma unroll
    for (int r = 0; r < 4; ++r) {
      int row = row0 + g * 4 + r;
      if (row < nrows)
        store_out(Y, (size_t)row * HID + col, acc[ct][r] + bias);
    }
  }
}

// ---------------------------------------------------------------------------
// Temporal scores via MFMA (split-T), persistent grid, 64 edges/block.
// Rolled head loop (low live-register count), biases in LDS, bounded regs.
// ---------------------------------------------------------------------------
__global__ __launch_bounds__(256, 4) void temporal_mfma_k(
    const float* __restrict__ T, const short* __restrict__ Wp,
    const float* __restrict__ btq, const float* __restrict__ btk,
    float* __restrict__ ts, int E, int ntiles) {
  __shared__ short Ws[2 * 8 * 4 * 16 * 8];  // 16KB
  __shared__ float bsh[256];                // [0..127]=btq, [128..255]=btk
  const int t = threadIdx.x;

  #pragma unroll
  for (int it = 0; it < 4; ++it) {
    int chunk = t + it * 256;
    *(bfrag8*)(&Ws[chunk * 8]) = *(const bfrag8*)(Wp + (size_t)chunk * 8);
  }
  bsh[t] = (t < 128) ? btq[t] : btk[t - 128];
  __syncthreads();

  const int w  = t >> 6;
  const int l  = t & 63;
  const int lr = l & 15;
  const int g  = l >> 4;

  for (int tile = blockIdx.x; tile < ntiles; tile += gridDim.x) {
    const int e0 = tile * 64 + w * 16;
    const int ar = min(e0 + lr, E - 1);
    const float* tp = T + (size_t)ar * 32 + g * 8;
    float xv[8];
    *(facc4*)(xv)     = *(const facc4*)(tp);
    *(facc4*)(xv + 4) = *(const facc4*)(tp + 4);
    bfrag8 ahi, alo;
    #pragma unroll
    for (int i = 0; i < 8; ++i) {
      short h = f2bf(xv[i]);
      ahi[i] = h;
      alo[i] = f2bf(xv[i] - bf2f(h));
    }
    const bool full = (e0 + 15 < E);

    #pragma unroll 1
    for (int ct = 0; ct < 8; ++ct) {
      float biasq = bsh[ct * 16 + lr];
      float biask = bsh[128 + ct * 16 + lr];
      facc4 accq = (facc4){biasq, biasq, biasq, biasq};
      bfrag8 bqf = *(const bfrag8*)(&Ws[((0 * 512) + ct * 64 + g * 16 + lr) * 8]);
      accq = __builtin_amdgcn_mfma_f32_16x16x32_bf16(alo, bqf, accq, 0, 0, 0);
      accq = __builtin_amdgcn_mfma_f32_16x16x32_bf16(ahi, bqf, accq, 0, 0, 0);
      facc4 acck = (facc4){biask, biask, biask, biask};
      bfrag8 bkf = *(const bfrag8*)(&Ws[((1 * 512) + ct * 64 + g * 16 + lr) * 8]);
      acck = __builtin_amdgcn_mfma_f32_16x16x32_bf16(alo, bkf, acck, 0, 0, 0);
      acck = __builtin_amdgcn_mfma_f32_16x16x32_bf16(ahi, bkf, acck, 0, 0, 0);

      float p[4];
      #pragma unroll
      for (int r = 0; r < 4; ++r) {
        float v = accq[r] * acck[r];
        v += __shfl_xor(v, 1, 16);
        v += __shfl_xor(v, 2, 16);
        v += __shfl_xor(v, 4, 16);
        v += __shfl_xor(v, 8, 16);
        p[r] = v;
      }
      if (lr == ct) {
        if (full) {
          #pragma unroll
          for (int r = 0; r < 4; ++r)
            ts[(size_t)(e0 + g * 4 + r) * 8 + ct] = p[r];
        } else {
          #pragma unroll
          for (int r = 0; r < 4; ++r) {
            int e = e0 + g * 4 + r;
            if (e < E) ts[(size_t)e * 8 + ct] = p[r];
          }
        }
      }
    }
  }
}

// ---------------------------------------------------------------------------
// CSR build
// ---------------------------------------------------------------------------
__global__ __launch_bounds__(256) void count_deg_k(const int* __restrict__ tgt,
                                                   int* __restrict__ deg, int E) {
  int gid = blockIdx.x * 256 + threadIdx.x;
  if (gid < E) atomicAdd(&deg[tgt[gid]], 1);
}

__global__ __launch_bounds__(256) void block_sum_k(const int* __restrict__ deg,
                                                   int* __restrict__ bsum, int n) {
  __shared__ int sd[256];
  const int base = blockIdx.x * 1024;
  const int t = threadIdx.x;
  int s = 0;
  #pragma unroll
  for (int j = 0; j < 4; ++j) {
    int i = base + t + j * 256;
    if (i < n) s += deg[i];
  }
  sd[t] = s;
  __syncthreads();
  for (int st = 128; st; st >>= 1) {
    if (t < st) sd[t] += sd[t + st];
    __syncthreads();
  }
  if (t == 0) bsum[blockIdx.x] = sd[0];
}

__global__ __launch_bounds__(1024) void scan_partials_k(const int* __restrict__ bsum,
                                                        int* __restrict__ boff, int G) {
  __shared__ int sd[1024];
  const int t = threadIdx.x;
  int v = (t < G) ? bsum[t] : 0;
  sd[t] = v;
  __syncthreads();
  for (int s = 1; s < 1024; s <<= 1) {
    int a = (t >= s) ? sd[t - s] : 0;
    __syncthreads();
    sd[t] += a;
    __syncthreads();
  }
  if (t < G) boff[t] = sd[t] - v;
}

__global__ __launch_bounds__(256) void block_scan_k(const int* __restrict__ deg,
                                                    const int* __restrict__ boff,
                                                    int* __restrict__ off, int n) {
  __shared__ int sd[256];
  const int base = blockIdx.x * 1024;
  const int t = threadIdx.x;
  const int i0 = base + t * 4;
  int v[4];
  int s = 0;
  #pragma unroll
  for (int j = 0; j < 4; ++j) {
    v[j] = (i0 + j < n) ? deg[i0 + j] : 0;
    s += v[j];
  }
  const int own = s;
  sd[t] = s;
  __syncthreads();
  for (int st = 1; st < 256; st <<= 1) {
    int a = (t >= st) ? sd[t - st] : 0;
    __syncthreads();
    sd[t] += a;
    __syncthreads();
  }
  int acc = boff[blockIdx.x] + sd[t] - own;
  #pragma unroll
  for (int j = 0; j < 4; ++j) {
    int idx = i0 + j;
    if (idx < n) {
      off[idx] = acc;
      acc += v[j];
      if (idx == n - 1) off[n] = acc;
    }
  }
}

__global__ __launch_bounds__(256) void scatter_k(const int* __restrict__ tgt,
                                                 const int* __restrict__ off,
                                                 int* __restrict__ cur,
                                                 int* __restrict__ elist, int E) {
  int gid = blockIdx.x * 256 + threadIdx.x;
  if (gid < E) {
    int n = tgt[gid];
    int p = atomicAdd(&cur[n], 1);
    elist[off[n] + p] = gid;
  }
}

// ---------------------------------------------------------------------------
// Per-node QK score + ONLINE softmax + aggregation in ONE gather pass.
// 32 lanes per node, lane g owns features g*4..g*4+3 (head h=g>>2, sub j=g&3).
// 8 nodes per 256-thread block; NO __syncthreads (per-group LDS slices,
// same-wave LDS ordering). Q/K/V bf16, 8B/lane gathers. agg stored bf16.
// ---------------------------------------------------------------------------
__global__ __launch_bounds__(256) void softmax_agg_k(
    const float* __restrict__ tscores, const short* __restrict__ Qp,
    const short* __restrict__ Kp, const short* __restrict__ Vp,
    const int* __restrict__ src, const int* __restrict__ off,
    const int* __restrict__ elist, float* __restrict__ attn_w,
    short* __restrict__ aggb, int N) {
  __shared__ int esh[8][MAXD];
  __shared__ int ssh[8][MAXD];
  __shared__ float sraw[8][MAXD][8];  // raw scores per head
  const int t = threadIdx.x;
  const int grp = t >> 5;
  const int g = t & 31;
  const int h = g >> 2;
  const int j = g & 3;
  const int n = blockIdx.x * 8 + grp;
  if (n >= N) return;

  const int s0 = off[n];
  const int deg = off[n + 1] - s0;

  float kr[4];
  {
    bf4 k4 = *(const bf4*)(Kp + (size_t)n * HID + g * 4);
    #pragma unroll
    for (int q = 0; q < 4; ++q) kr[q] = bf2f(k4[q]);
  }

  if (deg <= MAXD) {
    for (int i = g; i < deg; i += 32) {
      int e = elist[s0 + i];
      esh[grp][i] = e;
      ssh[grp][i] = src[e];
    }

    // single online pass: score + max + exp-sum + unnormalized aggregation
    float m = -3.0e38f, lsum = 0.f;
    float a0 = 0.f, a1 = 0.f, a2 = 0.f, a3 = 0.f;
    int i = 0;
    for (; i + 2 <= deg; i += 2) {
      int sn0 = ssh[grp][i], sn1 = ssh[grp][i + 1];
      int e0 = esh[grp][i], e1 = esh[grp][i + 1];
      bf4 q0 = *(const bf4*)(Qp + (size_t)sn0 * HID + g * 4);
      bf4 q1 = *(const bf4*)(Qp + (size_t)sn1 * HID + g * 4);
      bf4 v0 = *(const bf4*)(Vp + (size_t)sn0 * HID + g * 4);
      bf4 v1 = *(const bf4*)(Vp + (size_t)sn1 * HID + g * 4);
      float ts0 = tscores[(size_t)e0 * 8 + h];
      float ts1 = tscores[(size_t)e1 * 8 + h];
      float p0 = bf2f(q0[0]) * kr[0] + bf2f(q0[1]) * kr[1] +
                 bf2f(q0[2]) * kr[2] + bf2f(q0[3]) * kr[3];
      float p1 = bf2f(q1[0]) * kr[0] + bf2f(q1[1]) * kr[1] +
                 bf2f(q1[2]) * kr[2] + bf2f(q1[3]) * kr[3];
      p0 += __shfl_xor(p0, 1, 4); p0 += __shfl_xor(p0, 2, 4);
      p1 += __shfl_xor(p1, 1, 4); p1 += __shfl_xor(p1, 2, 4);
      float sc0 = ts0 + p0 * 0.25f;
      float sc1 = ts1 + p1 * 0.25f;
      if (j == 0) {
        sraw[grp][i][h] = sc0;
        sraw[grp][i + 1][h] = sc1;
      }
      float newm = fmaxf(fmaxf(m, sc0), sc1);
      float scale = __expf(m - newm);
      float w0 = __expf(sc0 - newm);
      float w1 = __expf(sc1 - newm);
      lsum = lsum * scale + w0 + w1;
      a0 = a0 * scale + w0 * bf2f(v0[0]) + w1 * bf2f(v1[0]);
      a1 = a1 * scale + w0 * bf2f(v0[1]) + w1 * bf2f(v1[1]);
      a2 = a2 * scale + w0 * bf2f(v0[2]) + w1 * bf2f(v1[2]);
      a3 = a3 * scale + w0 * bf2f(v0[3]) + w1 * bf2f(v1[3]);
      m = newm;
    }
    if (i < deg) {
      int sn0 = ssh[grp][i], e0 = esh[grp][i];
      bf4 q0 = *(const bf4*)(Qp + (size_t)sn0 * HID + g * 4);
      bf4 v0 = *(const bf4*)(Vp + (size_t)sn0 * HID + g * 4);
      float ts0 = tscores[(size_t)e0 * 8 + h];
      float p0 = bf2f(q0[0]) * kr[0] + bf2f(q0[1]) * kr[1] +
                 bf2f(q0[2]) * kr[2] + bf2f(q0[3]) * kr[3];
      p0 += __shfl_xor(p0, 1, 4); p0 += __shfl_xor(p0, 2, 4);
      float sc0 = ts0 + p0 * 0.25f;
      if (j == 0) sraw[grp][i][h] = sc0;
      float newm = fmaxf(m, sc0);
      float scale = __expf(m - newm);
      float w0 = __expf(sc0 - newm);
      lsum = lsum * scale + w0;
      a0 = a0 * scale + w0 * bf2f(v0[0]);
      a1 = a1 * scale + w0 * bf2f(v0[1]);
      a2 = a2 * scale + w0 * bf2f(v0[2]);
      a3 = a3 * scale + w0 * bf2f(v0[3]);
      m = newm;
    }
    float invl = (lsum > 0.f) ? 1.0f / lsum : 0.f;

    bf4 st;
    st[0] = f2bf(a0 * invl); st[1] = f2bf(a1 * invl);
    st[2] = f2bf(a2 * invl); st[3] = f2bf(a3 * invl);
    *(bf4*)(aggb + (size_t)n * HID + g * 4) = st;

    // attn_w tail: gather-free, j==0 lanes only
    if (j == 0) {
      for (int q = 0; q < deg; ++q) {
        float w = __expf(sraw[grp][q][h] - m) * invl;
        attn_w[(size_t)esh[grp][q] * 8 + h] = w;
      }
    }
  } else {
    // fallback (deg > MAXD): 3-pass unstaged
    float m = -3.0e38f;
    for (int q = 0; q < deg; ++q) {
      int e = elist[s0 + q];
      bf4 q4 = *(const bf4*)(Qp + (size_t)src[e] * HID + g * 4);
      float p = bf2f(q4[0]) * kr[0] + bf2f(q4[1]) * kr[1] +
                bf2f(q4[2]) * kr[2] + bf2f(q4[3]) * kr[3];
      p += __shfl_xor(p, 1, 4); p += __shfl_xor(p, 2, 4);
      m = fmaxf(m, tscores[(size_t)e * 8 + h] + p * 0.25f);
    }
    float l = 0.f;
    for (int q = 0; q < deg; ++q) {
      int e = elist[s0 + q];
      bf4 q4 = *(const bf4*)(Qp + (size_t)src[e] * HID + g * 4);
      float p = bf2f(q4[0]) * kr[0] + bf2f(q4[1]) * kr[1] +
                bf2f(q4[2]) * kr[2] + bf2f(q4[3]) * kr[3];
      p += __shfl_xor(p, 1, 4); p += __shfl_xor(p, 2, 4);
      l += __expf(tscores[(size_t)e * 8 + h] + p * 0.25f - m);
    }
    float invl = (l > 0.f) ? 1.0f / l : 0.f;
    float a0 = 0.f, a1 = 0.f, a2 = 0.f, a3 = 0.f;
    for (int q = 0; q < deg; ++q) {
      int e = elist[s0 + q];
      int sn = src[e];
      bf4 q4 = *(const bf4*)(Qp + (size_t)sn * HID + g * 4);
      float p = bf2f(q4[0]) * kr[0] + bf2f(q4[1]) * kr[1] +
                bf2f(q4[2]) * kr[2] + bf2f(q4[3]) * kr[3];
      p += __shfl_xor(p, 1, 4); p += __shfl_xor(p, 2, 4);
      float w = __expf(tscores[(size_t)e * 8 + h] + p * 0.25f - m) * invl;
      bf4 v4 = *(const bf4*)(Vp + (size_t)sn * HID + g * 4);
      a0 += w * bf2f(v4[0]);
      a1 += w * bf2f(v4[1]);
      a2 += w * bf2f(v4[2]);
      a3 += w * bf2f(v4[3]);
      if (j == 0) attn_w[(size_t)e * 8 + h] = w;
    }
    bf4 st;
    st[0] = f2bf(a0); st[1] = f2bf(a1); st[2] = f2bf(a2); st[3] = f2bf(a3);
    *(bf4*)(aggb + (size_t)n * HID + g * 4) = st;
  }
}

// ---------------------------------------------------------------------------
extern "C" void kernel_launch(void* const* d_in, const int* in_sizes, int n_in,
                              void* d_out, int out_size, void* d_ws, size_t ws_size,
                              hipStream_t stream) {
  const float* query    = (const float*)d_in[0];
  const float* key      = (const float*)d_in[1];
  const float* value    = (const float*)d_in[2];
  const float* temporal = (const float*)d_in[3];
  const int*   eidx     = (const int*)d_in[4];
  const float* Wq   = (const float*)d_in[5];
  const float* bq   = (const float*)d_in[6];
  const float* Wk   = (const float*)d_in[7];
  const float* bk   = (const float*)d_in[8];
  const float* Wv   = (const float*)d_in[9];
  const float* bv   = (const float*)d_in[10];
  const float* Wtq  = (const float*)d_in[11];
  const float* btq  = (const float*)d_in[12];
  const float* Wtk  = (const float*)d_in[13];
  const float* btk  = (const float*)d_in[14];
  const float* Wout = (const float*)d_in[15];
  const float* bout = (const float*)d_in[16];

  const int N = in_sizes[0] / HID;
  const int E = in_sizes[4] / 2;
  const int* src = eidx;
  const int* tgt = eidx + E;

  char* ws = (char*)d_ws;
  short* Qp = (short*)ws;                      ws += (size_t)N * HID * 2;
  short* Kp = (short*)ws;                      ws += (size_t)N * HID * 2;
  short* Vp = (short*)ws;                      ws += (size_t)N * HID * 2;
  short* aggb = (short*)ws;                    ws += (size_t)N * HID * 2;
  float* tscores = (float*)ws;                 ws += (size_t)E * 8 * 4;
  int* deg   = (int*)ws;                       ws += (size_t)N * 4;
  int* cur   = (int*)ws;                       ws += (size_t)N * 4;
  int* off   = (int*)ws;                       ws += (size_t)(N + 1) * 4;
  int* elist = (int*)ws;                       ws += (size_t)E * 4;
  int* bsum  = (int*)ws;                       ws += 1024 * 4;
  int* boff  = (int*)ws;                       ws += 1024 * 4;
  short* Wpre = (short*)ws;                    // 9216 * 16B = 147456 B

  const int G = (N + 1023) / 1024;

  hipMemsetAsync(deg, 0, sizeof(int) * 2 * (size_t)N, stream);  // deg + cur

  dim3 b256(256);
  preformat_k<<<36, b256, 0, stream>>>(Wq, Wk, Wv, Wout, Wtq, Wtk, Wpre);

  const int gblk = (N + 63) / 64;
  gemm_mfma_k<float, short><<<gblk, b256, 0, stream>>>(query, Wpre + 0 * 16384, bq, Qp, N);
  gemm_mfma_k<float, short><<<gblk, b256, 0, stream>>>(key,   Wpre + 1 * 16384, bk, Kp, N);
  gemm_mfma_k<float, short><<<gblk, b256, 0, stream>>>(value, Wpre + 2 * 16384, bv, Vp, N);

  temporal_mfma_k<<<2048, b256, 0, stream>>>(temporal, Wpre + 4 * 16384, btq, btk,
                                             tscores, E, (E + 63) / 64);

  count_deg_k<<<(E + 255) / 256, b256, 0, stream>>>(tgt, deg, E);
  block_sum_k<<<G, b256, 0, stream>>>(deg, bsum, N);
  scan_partials_k<<<1, 1024, 0, stream>>>(bsum, boff, G);
  block_scan_k<<<G, b256, 0, stream>>>(deg, boff, off, N);
  scatter_k<<<(E + 255) / 256, b256, 0, stream>>>(tgt, off, cur, elist, E);

  float* attn_w = (float*)d_out + (size_t)N * HID;
  softmax_agg_k<<<(N + 7) / 8, b256, 0, stream>>>(tscores, Qp, Kp, Vp, src, off,
                                                  elist, attn_w, aggb, N);

  gemm_mfma_k<short, float><<<gblk, b256, 0, stream>>>(aggb, Wpre + 3 * 16384, bout,
                                                       (float*)d_out, N);
}

// Round 7
// 283.567 us; speedup vs baseline: 3.1997x; 1.1113x over previous
//
#include <hip/hip_runtime.h>
#include <hip/hip_bf16.h>

#define HID 128
#define MAXD 64  // per-node fast-path degree cap (Poisson(6) max ~25)

typedef __attribute__((ext_vector_type(8))) short bfrag8;
typedef __attribute__((ext_vector_type(4))) short bf4;
typedef __attribute__((ext_vector_type(4))) float facc4;

// f32 -> bf16 bits, round-to-nearest-even
__device__ inline short f2bf(float x) {
  unsigned u = __builtin_bit_cast(unsigned, x);
  u += 0x7fffu + ((u >> 16) & 1u);
  return (short)(u >> 16);
}
__device__ inline float bf2f(short s) {
  unsigned u = ((unsigned)(unsigned short)s) << 16;
  return __builtin_bit_cast(float, u);
}

__device__ inline void store_out(float* Y, size_t i, float v) { Y[i] = v; }
__device__ inline void store_out(short* Y, size_t i, float v) { Y[i] = f2bf(v); }

// ---------------------------------------------------------------------------
// One-shot weight pre-format: f32 W -> fragment-linear bf16 chunks.
// Chunks 0..8191: Wq,Wk,Wv,Wout (2048 each), layout ct<<8|kt<<6|g<<4|c.
// Chunks 8192..9215: [Wtq|Wtk] (1024), layout qk<<9|ct<<6|g<<4|c.
// ---------------------------------------------------------------------------
__global__ __launch_bounds__(256) void preformat_k(
    const float* __restrict__ Wq, const float* __restrict__ Wk,
    const float* __restrict__ Wv, const float* __restrict__ Wout,
    const float* __restrict__ Wtq, const float* __restrict__ Wtk,
    short* __restrict__ out) {
  int gid = blockIdx.x * 256 + threadIdx.x;
  if (gid >= 9216) return;
  bfrag8 v;
  if (gid < 8192) {
    int which = gid >> 11;
    int chunk = gid & 2047;
    const float* W = (which == 0) ? Wq : (which == 1) ? Wk
                   : (which == 2) ? Wv : Wout;
    int c  = chunk & 15;
    int g  = (chunk >> 4) & 3;
    int kt = (chunk >> 6) & 3;
    int ct = chunk >> 8;
    int col = ct * 16 + c;
    int k0 = kt * 32 + g * 8;
    #pragma unroll
    for (int i = 0; i < 8; ++i) v[i] = f2bf(W[(size_t)(k0 + i) * HID + col]);
  } else {
    int chunk = gid - 8192;
    int c  = chunk & 15;
    int g  = (chunk >> 4) & 3;
    int ct = (chunk >> 6) & 7;
    int qk = chunk >> 9;
    const float* W = qk ? Wtk : Wtq;
    int col = ct * 16 + c;
    int k0 = g * 8;
    #pragma unroll
    for (int i = 0; i < 8; ++i) v[i] = f2bf(W[(size_t)(k0 + i) * HID + col]);
  }
  *(bfrag8*)(out + (size_t)gid * 8) = v;
}

// ---------------------------------------------------------------------------
// Y[r,c] = X[r,:128] @ W[:128,c] + b[c] via bf16 MFMA.
// IT=float: split-X (hi+lo, 2 MFMA). IT=short(bf16): direct (1 MFMA).
// W pre-formatted bf16 chunks; prologue is a pure 16B copy.
// ---------------------------------------------------------------------------
template <typename IT, typename OT>
__global__ __launch_bounds__(256) void gemm_mfma_k(
    const IT* __restrict__ X, const short* __restrict__ Wp,
    const float* __restrict__ b, OT* __restrict__ Y, int nrows) {
  __shared__ short Ws[8 * 4 * 4 * 16 * 8];  // 32KB
  const int t = threadIdx.x;

  #pragma unroll
  for (int it = 0; it < 8; ++it) {
    int chunk = t + it * 256;
    *(bfrag8*)(&Ws[chunk * 8]) = *(const bfrag8*)(Wp + (size_t)chunk * 8);
  }
  __syncthreads();

  const int w  = t >> 6;
  const int l  = t & 63;
  const int lr = l & 15;
  const int g  = l >> 4;
  const int row0 = blockIdx.x * 64 + w * 16;
  const int arow = min(row0 + lr, nrows - 1);

  facc4 acc[8];
  #pragma unroll
  for (int i = 0; i < 8; ++i) acc[i] = (facc4){0.f, 0.f, 0.f, 0.f};

  #pragma unroll
  for (int kt = 0; kt < 4; ++kt) {
    if constexpr (sizeof(IT) == 4) {
      const float* xp = (const float*)X + (size_t)arow * HID + kt * 32 + g * 8;
      float xv[8];
      *(facc4*)(xv)     = *(const facc4*)(xp);
      *(facc4*)(xv + 4) = *(const facc4*)(xp + 4);
      bfrag8 ahi, alo;
      #pragma unroll
      for (int i = 0; i < 8; ++i) {
        short h = f2bf(xv[i]);
        ahi[i] = h;
        alo[i] = f2bf(xv[i] - bf2f(h));
      }
      #pragma unroll
      for (int ct = 0; ct < 8; ++ct) {
        bfrag8 bf = *(const bfrag8*)(&Ws[(((ct * 4 + kt) * 4 + g) * 16 + lr) * 8]);
        acc[ct] = __builtin_amdgcn_mfma_f32_16x16x32_bf16(alo, bf, acc[ct], 0, 0, 0);
        acc[ct] = __builtin_amdgcn_mfma_f32_16x16x32_bf16(ahi, bf, acc[ct], 0, 0, 0);
      }
    } else {
      bfrag8 a = *(const bfrag8*)((const short*)X + (size_t)arow * HID + kt * 32 + g * 8);
      #pragma unroll
      for (int ct = 0; ct < 8; ++ct) {
        bfrag8 bf = *(const bfrag8*)(&Ws[(((ct * 4 + kt) * 4 + g) * 16 + lr) * 8]);
        acc[ct] = __builtin_amdgcn_mfma_f32_16x16x32_bf16(a, bf, acc[ct], 0, 0, 0);
      }
    }
  }

  #pragma unroll
  for (int ct = 0; ct < 8; ++ct) {
    int col = ct * 16 + lr;
    float bias = b[col];
    #pragma unroll
    for (int r = 0; r < 4; ++r) {
      int row = row0 + g * 4 + r;
      if (row < nrows)
        store_out(Y, (size_t)row * HID + col, acc[ct][r] + bias);
    }
  }
}

// ---------------------------------------------------------------------------
// Temporal scores via MFMA, edges-on-COLUMNS mapping:
//   A = W fragment (rows = feature-within-head, k = temporal dim)
//   B = T^T fragment (k = temporal dim, cols = edges)  [same per-lane data
//       layout as the old A-load: lane c loads T[e0+c, g*8..g*8+8)]
// Each lane then holds 4 features of ONE edge -> head-dot = 4 in-lane FMAs
// + 2 shuffles (vs 4x4-deep shuffle chains). Split-T on the B operand.
// ---------------------------------------------------------------------------
__global__ __launch_bounds__(256, 8) void temporal_mfma_k(
    const float* __restrict__ T, const short* __restrict__ Wp,
    const float* __restrict__ btq, const float* __restrict__ btk,
    float* __restrict__ ts, int E, int ntiles) {
  __shared__ short Ws[2 * 8 * 4 * 16 * 8];  // 16KB
  __shared__ float bsh[256];                // [0..127]=btq, [128..255]=btk
  const int t = threadIdx.x;

  #pragma unroll
  for (int it = 0; it < 4; ++it) {
    int chunk = t + it * 256;
    *(bfrag8*)(&Ws[chunk * 8]) = *(const bfrag8*)(Wp + (size_t)chunk * 8);
  }
  bsh[t] = (t < 128) ? btq[t] : btk[t - 128];
  __syncthreads();

  const int w = t >> 6;
  const int l = t & 63;
  const int c = l & 15;  // edge within 16-edge wave tile (MFMA column)
  const int g = l >> 4;  // k-group / feature-row group

  for (int tile = blockIdx.x; tile < ntiles; tile += gridDim.x) {
    const int e0 = tile * 64 + w * 16;
    const int ar = min(e0 + c, E - 1);
    const float* tp = T + (size_t)ar * 32 + g * 8;
    float xv[8];
    *(facc4*)(xv)     = *(const facc4*)(tp);
    *(facc4*)(xv + 4) = *(const facc4*)(tp + 4);
    bfrag8 thi, tlo;
    #pragma unroll
    for (int i = 0; i < 8; ++i) {
      short hh = f2bf(xv[i]);
      thi[i] = hh;
      tlo[i] = f2bf(xv[i] - bf2f(hh));
    }
    const bool full = (e0 + 15 < E);

    #pragma unroll 1
    for (int ct = 0; ct < 8; ++ct) {
      facc4 accq = *(const facc4*)(&bsh[ct * 16 + g * 4]);        // btq rows
      bfrag8 wq = *(const bfrag8*)(&Ws[(ct * 64 + g * 16 + c) * 8]);
      accq = __builtin_amdgcn_mfma_f32_16x16x32_bf16(wq, tlo, accq, 0, 0, 0);
      accq = __builtin_amdgcn_mfma_f32_16x16x32_bf16(wq, thi, accq, 0, 0, 0);
      facc4 acck = *(const facc4*)(&bsh[128 + ct * 16 + g * 4]);  // btk rows
      bfrag8 wk = *(const bfrag8*)(&Ws[(512 + ct * 64 + g * 16 + c) * 8]);
      acck = __builtin_amdgcn_mfma_f32_16x16x32_bf16(wk, tlo, acck, 0, 0, 0);
      acck = __builtin_amdgcn_mfma_f32_16x16x32_bf16(wk, thi, acck, 0, 0, 0);

      float s = accq[0] * acck[0] + accq[1] * acck[1] +
                accq[2] * acck[2] + accq[3] * acck[3];
      s += __shfl_xor(s, 16, 64);
      s += __shfl_xor(s, 32, 64);
      if (g == (ct & 3)) {
        int e = e0 + c;
        if (full || e < E) ts[(size_t)e * 8 + ct] = s;
      }
    }
  }
}

// ---------------------------------------------------------------------------
// CSR build
// ---------------------------------------------------------------------------
__global__ __launch_bounds__(256) void count_deg_k(const int* __restrict__ tgt,
                                                   int* __restrict__ deg, int E) {
  int gid = blockIdx.x * 256 + threadIdx.x;
  if (gid < E) atomicAdd(&deg[tgt[gid]], 1);
}

__global__ __launch_bounds__(256) void block_sum_k(const int* __restrict__ deg,
                                                   int* __restrict__ bsum, int n) {
  __shared__ int sd[256];
  const int base = blockIdx.x * 1024;
  const int t = threadIdx.x;
  int s = 0;
  #pragma unroll
  for (int j = 0; j < 4; ++j) {
    int i = base + t + j * 256;
    if (i < n) s += deg[i];
  }
  sd[t] = s;
  __syncthreads();
  for (int st = 128; st; st >>= 1) {
    if (t < st) sd[t] += sd[t + st];
    __syncthreads();
  }
  if (t == 0) bsum[blockIdx.x] = sd[0];
}

__global__ __launch_bounds__(1024) void scan_partials_k(const int* __restrict__ bsum,
                                                        int* __restrict__ boff, int G) {
  __shared__ int sd[1024];
  const int t = threadIdx.x;
  int v = (t < G) ? bsum[t] : 0;
  sd[t] = v;
  __syncthreads();
  for (int s = 1; s < 1024; s <<= 1) {
    int a = (t >= s) ? sd[t - s] : 0;
    __syncthreads();
    sd[t] += a;
    __syncthreads();
  }
  if (t < G) boff[t] = sd[t] - v;
}

__global__ __launch_bounds__(256) void block_scan_k(const int* __restrict__ deg,
                                                    const int* __restrict__ boff,
                                                    int* __restrict__ off, int n) {
  __shared__ int sd[256];
  const int base = blockIdx.x * 1024;
  const int t = threadIdx.x;
  const int i0 = base + t * 4;
  int v[4];
  int s = 0;
  #pragma unroll
  for (int j = 0; j < 4; ++j) {
    v[j] = (i0 + j < n) ? deg[i0 + j] : 0;
    s += v[j];
  }
  const int own = s;
  sd[t] = s;
  __syncthreads();
  for (int st = 1; st < 256; st <<= 1) {
    int a = (t >= st) ? sd[t - st] : 0;
    __syncthreads();
    sd[t] += a;
    __syncthreads();
  }
  int acc = boff[blockIdx.x] + sd[t] - own;
  #pragma unroll
  for (int j = 0; j < 4; ++j) {
    int idx = i0 + j;
    if (idx < n) {
      off[idx] = acc;
      acc += v[j];
      if (idx == n - 1) off[n] = acc;
    }
  }
}

__global__ __launch_bounds__(256) void scatter_k(const int* __restrict__ tgt,
                                                 const int* __restrict__ off,
                                                 int* __restrict__ cur,
                                                 int* __restrict__ elist, int E) {
  int gid = blockIdx.x * 256 + threadIdx.x;
  if (gid < E) {
    int n = tgt[gid];
    int p = atomicAdd(&cur[n], 1);
    elist[off[n] + p] = gid;
  }
}

// ---------------------------------------------------------------------------
// Per-node QK score + softmax + aggregation, ONE gather pass, NO max-tracking
// (scores bounded ~|30| << 88, fp32 exp is safe; softmax is shift-invariant so
// result is mathematically identical to the max-subtracted reference).
// 32 lanes per node, lane g owns features g*4..g*4+3 (head h=g>>2, sub j=g&3).
// 8 nodes per 256-thread block; NO __syncthreads (per-group LDS slices,
// same-wave LDS ordering). Q/K/V bf16, 8B/lane gathers. agg stored bf16.
// ---------------------------------------------------------------------------
__global__ __launch_bounds__(256) void softmax_agg_k(
    const float* __restrict__ tscores, const short* __restrict__ Qp,
    const short* __restrict__ Kp, const short* __restrict__ Vp,
    const int* __restrict__ src, const int* __restrict__ off,
    const int* __restrict__ elist, float* __restrict__ attn_w,
    short* __restrict__ aggb, int N) {
  __shared__ int esh[8][MAXD];
  __shared__ int ssh[8][MAXD];
  __shared__ float sraw[8][MAXD][8];  // unnormalized exp weights per head
  const int t = threadIdx.x;
  const int grp = t >> 5;
  const int g = t & 31;
  const int h = g >> 2;
  const int j = g & 3;
  const int n = blockIdx.x * 8 + grp;
  if (n >= N) return;

  const int s0 = off[n];
  const int deg = off[n + 1] - s0;

  float kr[4];
  {
    bf4 k4 = *(const bf4*)(Kp + (size_t)n * HID + g * 4);
    #pragma unroll
    for (int q = 0; q < 4; ++q) kr[q] = bf2f(k4[q]);
  }

  if (deg <= MAXD) {
    for (int i = g; i < deg; i += 32) {
      int e = elist[s0 + i];
      esh[grp][i] = e;
      ssh[grp][i] = src[e];
    }

    float lsum = 0.f;
    float a0 = 0.f, a1 = 0.f, a2 = 0.f, a3 = 0.f;
    int i = 0;
    for (; i + 2 <= deg; i += 2) {
      int sn0 = ssh[grp][i], sn1 = ssh[grp][i + 1];
      int e0 = esh[grp][i], e1 = esh[grp][i + 1];
      bf4 q0 = *(const bf4*)(Qp + (size_t)sn0 * HID + g * 4);
      bf4 q1 = *(const bf4*)(Qp + (size_t)sn1 * HID + g * 4);
      bf4 v0 = *(const bf4*)(Vp + (size_t)sn0 * HID + g * 4);
      bf4 v1 = *(const bf4*)(Vp + (size_t)sn1 * HID + g * 4);
      float ts0 = tscores[(size_t)e0 * 8 + h];
      float ts1 = tscores[(size_t)e1 * 8 + h];
      float p0 = bf2f(q0[0]) * kr[0] + bf2f(q0[1]) * kr[1] +
                 bf2f(q0[2]) * kr[2] + bf2f(q0[3]) * kr[3];
      float p1 = bf2f(q1[0]) * kr[0] + bf2f(q1[1]) * kr[1] +
                 bf2f(q1[2]) * kr[2] + bf2f(q1[3]) * kr[3];
      p0 += __shfl_xor(p0, 1, 4); p0 += __shfl_xor(p0, 2, 4);
      p1 += __shfl_xor(p1, 1, 4); p1 += __shfl_xor(p1, 2, 4);
      float w0 = __expf(ts0 + p0 * 0.25f);
      float w1 = __expf(ts1 + p1 * 0.25f);
      if (j == 0) {
        sraw[grp][i][h] = w0;
        sraw[grp][i + 1][h] = w1;
      }
      lsum += w0 + w1;
      a0 += w0 * bf2f(v0[0]) + w1 * bf2f(v1[0]);
      a1 += w0 * bf2f(v0[1]) + w1 * bf2f(v1[1]);
      a2 += w0 * bf2f(v0[2]) + w1 * bf2f(v1[2]);
      a3 += w0 * bf2f(v0[3]) + w1 * bf2f(v1[3]);
    }
    if (i < deg) {
      int sn0 = ssh[grp][i], e0 = esh[grp][i];
      bf4 q0 = *(const bf4*)(Qp + (size_t)sn0 * HID + g * 4);
      bf4 v0 = *(const bf4*)(Vp + (size_t)sn0 * HID + g * 4);
      float ts0 = tscores[(size_t)e0 * 8 + h];
      float p0 = bf2f(q0[0]) * kr[0] + bf2f(q0[1]) * kr[1] +
                 bf2f(q0[2]) * kr[2] + bf2f(q0[3]) * kr[3];
      p0 += __shfl_xor(p0, 1, 4); p0 += __shfl_xor(p0, 2, 4);
      float w0 = __expf(ts0 + p0 * 0.25f);
      if (j == 0) sraw[grp][i][h] = w0;
      lsum += w0;
      a0 += w0 * bf2f(v0[0]);
      a1 += w0 * bf2f(v0[1]);
      a2 += w0 * bf2f(v0[2]);
      a3 += w0 * bf2f(v0[3]);
    }
    float invl = (lsum > 0.f) ? 1.0f / lsum : 0.f;

    bf4 st;
    st[0] = f2bf(a0 * invl); st[1] = f2bf(a1 * invl);
    st[2] = f2bf(a2 * invl); st[3] = f2bf(a3 * invl);
    *(bf4*)(aggb + (size_t)n * HID + g * 4) = st;

    // attn_w tail: gather-free and exp-free, j==0 lanes only
    if (j == 0) {
      for (int q = 0; q < deg; ++q)
        attn_w[(size_t)esh[grp][q] * 8 + h] = sraw[grp][q][h] * invl;
    }
  } else {
    // fallback (deg > MAXD): 3-pass unstaged, max-subtracted
    float m = -3.0e38f;
    for (int q = 0; q < deg; ++q) {
      int e = elist[s0 + q];
      bf4 q4 = *(const bf4*)(Qp + (size_t)src[e] * HID + g * 4);
      float p = bf2f(q4[0]) * kr[0] + bf2f(q4[1]) * kr[1] +
                bf2f(q4[2]) * kr[2] + bf2f(q4[3]) * kr[3];
      p += __shfl_xor(p, 1, 4); p += __shfl_xor(p, 2, 4);
      m = fmaxf(m, tscores[(size_t)e * 8 + h] + p * 0.25f);
    }
    float l = 0.f;
    for (int q = 0; q < deg; ++q) {
      int e = elist[s0 + q];
      bf4 q4 = *(const bf4*)(Qp + (size_t)src[e] * HID + g * 4);
      float p = bf2f(q4[0]) * kr[0] + bf2f(q4[1]) * kr[1] +
                bf2f(q4[2]) * kr[2] + bf2f(q4[3]) * kr[3];
      p += __shfl_xor(p, 1, 4); p += __shfl_xor(p, 2, 4);
      l += __expf(tscores[(size_t)e * 8 + h] + p * 0.25f - m);
    }
    float invl = (l > 0.f) ? 1.0f / l : 0.f;
    float a0 = 0.f, a1 = 0.f, a2 = 0.f, a3 = 0.f;
    for (int q = 0; q < deg; ++q) {
      int e = elist[s0 + q];
      int sn = src[e];
      bf4 q4 = *(const bf4*)(Qp + (size_t)sn * HID + g * 4);
      float p = bf2f(q4[0]) * kr[0] + bf2f(q4[1]) * kr[1] +
                bf2f(q4[2]) * kr[2] + bf2f(q4[3]) * kr[3];
      p += __shfl_xor(p, 1, 4); p += __shfl_xor(p, 2, 4);
      float w = __expf(tscores[(size_t)e * 8 + h] + p * 0.25f - m) * invl;
      bf4 v4 = *(const bf4*)(Vp + (size_t)sn * HID + g * 4);
      a0 += w * bf2f(v4[0]);
      a1 += w * bf2f(v4[1]);
      a2 += w * bf2f(v4[2]);
      a3 += w * bf2f(v4[3]);
      if (j == 0) attn_w[(size_t)e * 8 + h] = w;
    }
    bf4 st;
    st[0] = f2bf(a0); st[1] = f2bf(a1); st[2] = f2bf(a2); st[3] = f2bf(a3);
    *(bf4*)(aggb + (size_t)n * HID + g * 4) = st;
  }
}

// ---------------------------------------------------------------------------
extern "C" void kernel_launch(void* const* d_in, const int* in_sizes, int n_in,
                              void* d_out, int out_size, void* d_ws, size_t ws_size,
                              hipStream_t stream) {
  const float* query    = (const float*)d_in[0];
  const float* key      = (const float*)d_in[1];
  const float* value    = (const float*)d_in[2];
  const float* temporal = (const float*)d_in[3];
  const int*   eidx     = (const int*)d_in[4];
  const float* Wq   = (const float*)d_in[5];
  const float* bq   = (const float*)d_in[6];
  const float* Wk   = (const float*)d_in[7];
  const float* bk   = (const float*)d_in[8];
  const float* Wv   = (const float*)d_in[9];
  const float* bv   = (const float*)d_in[10];
  const float* Wtq  = (const float*)d_in[11];
  const float* btq  = (const float*)d_in[12];
  const float* Wtk  = (const float*)d_in[13];
  const float* btk  = (const float*)d_in[14];
  const float* Wout = (const float*)d_in[15];
  const float* bout = (const float*)d_in[16];

  const int N = in_sizes[0] / HID;
  const int E = in_sizes[4] / 2;
  const int* src = eidx;
  const int* tgt = eidx + E;

  char* ws = (char*)d_ws;
  short* Qp = (short*)ws;                      ws += (size_t)N * HID * 2;
  short* Kp = (short*)ws;                      ws += (size_t)N * HID * 2;
  short* Vp = (short*)ws;                      ws += (size_t)N * HID * 2;
  short* aggb = (short*)ws;                    ws += (size_t)N * HID * 2;
  float* tscores = (float*)ws;                 ws += (size_t)E * 8 * 4;
  int* deg   = (int*)ws;                       ws += (size_t)N * 4;
  int* cur   = (int*)ws;                       ws += (size_t)N * 4;
  int* off   = (int*)ws;                       ws += (size_t)(N + 1) * 4;
  int* elist = (int*)ws;                       ws += (size_t)E * 4;
  int* bsum  = (int*)ws;                       ws += 1024 * 4;
  int* boff  = (int*)ws;                       ws += 1024 * 4;
  short* Wpre = (short*)ws;                    // 9216 * 16B = 147456 B

  const int G = (N + 1023) / 1024;

  hipMemsetAsync(deg, 0, sizeof(int) * 2 * (size_t)N, stream);  // deg + cur

  dim3 b256(256);
  preformat_k<<<36, b256, 0, stream>>>(Wq, Wk, Wv, Wout, Wtq, Wtk, Wpre);

  const int gblk = (N + 63) / 64;
  gemm_mfma_k<float, short><<<gblk, b256, 0, stream>>>(query, Wpre + 0 * 16384, bq, Qp, N);
  gemm_mfma_k<float, short><<<gblk, b256, 0, stream>>>(key,   Wpre + 1 * 16384, bk, Kp, N);
  gemm_mfma_k<float, short><<<gblk, b256, 0, stream>>>(value, Wpre + 2 * 16384, bv, Vp, N);

  temporal_mfma_k<<<2048, b256, 0, stream>>>(temporal, Wpre + 4 * 16384, btq, btk,
                                             tscores, E, (E + 63) / 64);

  count_deg_k<<<(E + 255) / 256, b256, 0, stream>>>(tgt, deg, E);
  block_sum_k<<<G, b256, 0, stream>>>(deg, bsum, N);
  scan_partials_k<<<1, 1024, 0, stream>>>(bsum, boff, G);
  block_scan_k<<<G, b256, 0, stream>>>(deg, boff, off, N);
  scatter_k<<<(E + 255) / 256, b256, 0, stream>>>(tgt, off, cur, elist, E);

  float* attn_w = (float*)d_out + (size_t)N * HID;
  softmax_agg_k<<<(N + 7) / 8, b256, 0, stream>>>(tscores, Qp, Kp, Vp, src, off,
                                                  elist, attn_w, aggb, N);

  gemm_mfma_k<short, float><<<gblk, b256, 0, stream>>>(aggb, Wpre + 3 * 16384, bout,
                                                       (float*)d_out, N);
}